// Round 2
// baseline (1718.841 us; speedup 1.0000x reference)
//
#include <hip/hip_runtime.h>
#include <hip/hip_fp16.h>

// SpectralAttention: B=4, S=1024, E=1024, H=16, HD=64.
// Identity: real(ifft2(F*exp(i*phi))) == ifft2(F * cos(phi)) for real scores,
// phi = alpha*atan(log|F|+eps) symmetric under (u,v)->(-u,-v). So the spectral
// filter is a REAL gain => Hermitian half-spectrum, no bit-reversal fixups.
//
// Workspace (66 MiB max — conservative vs unknown ws_size):
//   0      Q   bf16 [bh][s][d]   8 MiB
//   8 MiB  Kb  bf16 [bh][s][d]   8 MiB
//   16 MiB Vt  bf16 [bh][d][s]   8 MiB
//   24 MiB ctx bf16 [bh][s][d]   8 MiB
//   32 MiB Sc  fp16 [8][s][k]   16 MiB   (aliased: attn bf16, same size)
//   48 MiB Cbuf half2 [8][1024][513] ~16.03 MiB
//   65 MiB flags: [0]=isf32, [1]=alpha(f32)
// Input dtype (bf16 vs fp32) detected at runtime by k0 (see notes above).

typedef __attribute__((ext_vector_type(8))) short short8;
typedef __attribute__((ext_vector_type(4))) float f32x4;

#define PITCH 40  // LDS row pitch (bf16 elems): 80B rows, 16B aligned slots

__device__ __forceinline__ float bf2f(short v) {
  return __uint_as_float(((unsigned)(unsigned short)v) << 16);
}
__device__ __forceinline__ short f2bf(float f) {
  unsigned u = __float_as_uint(f);
  u += 0x7FFFu + ((u >> 16) & 1u);  // RNE
  return (short)(u >> 16);
}

// Load 8 contiguous elems at `idx` as bf16x8, from bf16 or fp32 storage.
__device__ __forceinline__ short8 ld8(const void* p, size_t idx, int isf32) {
  short8 r;
  if (isf32) {
    const float* f = (const float*)p + idx;
    float4 a = *(const float4*)f;
    float4 b = *(const float4*)(f + 4);
    r[0] = f2bf(a.x); r[1] = f2bf(a.y); r[2] = f2bf(a.z); r[3] = f2bf(a.w);
    r[4] = f2bf(b.x); r[5] = f2bf(b.y); r[6] = f2bf(b.z); r[7] = f2bf(b.w);
  } else {
    r = *(const short8*)((const short*)p + idx);
  }
  return r;
}
__device__ __forceinline__ float ldf(const void* p, int idx, int isf32) {
  return isf32 ? ((const float*)p)[idx] : bf2f(((const short*)p)[idx]);
}

// ------------------------------------------------- k0: dtype detect + alpha
// bf16 storage: low halves of words are genuine N(0,1) bf16 (max ~6, never 0).
// fp32 storage: low halves are mantissa bits -> max is astronomical, OR all
// zero (if tensors were bf16-rounded then upcast).
__global__ void k0_detect(const unsigned* __restrict__ q,
                          const void* __restrict__ alphap, int* __restrict__ flags) {
  __shared__ float smax[256];
  __shared__ int szero[256];
  int t = threadIdx.x;
  float mx = 0.f; int zc = 0;
  for (int i = t; i < 16384; i += 256) {
    unsigned w = q[i];
    unsigned lo = w & 0xFFFFu;
    float v = fabsf(__uint_as_float(lo << 16));
    if (!(v <= 1e30f)) v = 1e30f;  // NaN/Inf -> large
    mx = fmaxf(mx, v);
    zc += (lo == 0u);
  }
  smax[t] = mx; szero[t] = zc;
  __syncthreads();
  for (int s = 128; s > 0; s >>= 1) {
    if (t < s) { smax[t] = fmaxf(smax[t], smax[t + s]); szero[t] += szero[t + s]; }
    __syncthreads();
  }
  if (t == 0) {
    int isf32 = (smax[0] > 100.f) || (szero[0] > 12288);
    flags[0] = isf32;
    float alpha = isf32 ? *(const float*)alphap
                        : bf2f(*(const short*)alphap);
    ((float*)flags)[1] = alpha;
  }
}

// ------------------------------------------------- k1: QKV projection
__global__ __launch_bounds__(256) void k1_qkv(
    const void* __restrict__ x,
    const void* __restrict__ Wq, const void* __restrict__ bq,
    const void* __restrict__ Wk, const void* __restrict__ bk,
    const void* __restrict__ Wv, const void* __restrict__ bv,
    short* __restrict__ Qo, short* __restrict__ Ko, short* __restrict__ Vt,
    const int* __restrict__ flags)
{
  __shared__ __align__(16) short As[128 * PITCH];
  __shared__ __align__(16) short Bs[128 * PITCH];
  const int isf32 = flags[0];
  const int t = threadIdx.x;
  const int m0 = blockIdx.x * 128, n0 = blockIdx.y * 128;
  const int which = blockIdx.z;
  const void* __restrict__ W = (which == 0) ? Wq : (which == 1) ? Wk : Wv;
  const void* __restrict__ bias = (which == 0) ? bq : (which == 1) ? bk : bv;
  const int lane = t & 63, wvi = t >> 6;
  const int wr = wvi >> 1, wc = wvi & 1;
  const int lm = lane & 15, lq = lane >> 4;
  f32x4 acc[4][4] = {};

  for (int k0 = 0; k0 < 1024; k0 += 32) {
    __syncthreads();
#pragma unroll
    for (int i = 0; i < 2; ++i) {
      int l = t + i * 256;
      int row = l >> 2, kk = (l & 3) << 3;
      *(short8*)&As[row * PITCH + kk] = ld8(x, (size_t)(m0 + row) * 1024 + k0 + kk, isf32);
      *(short8*)&Bs[row * PITCH + kk] = ld8(W, (size_t)(n0 + row) * 1024 + k0 + kk, isf32);
    }
    __syncthreads();
    short8 af[4], bf[4];
#pragma unroll
    for (int a = 0; a < 4; ++a) af[a] = *(const short8*)&As[(wr * 64 + a * 16 + lm) * PITCH + lq * 8];
#pragma unroll
    for (int b = 0; b < 4; ++b) bf[b] = *(const short8*)&Bs[(wc * 64 + b * 16 + lm) * PITCH + lq * 8];
#pragma unroll
    for (int a = 0; a < 4; ++a)
#pragma unroll
      for (int b = 0; b < 4; ++b)
        acc[a][b] = __builtin_amdgcn_mfma_f32_16x16x32_bf16(af[a], bf[b], acc[a][b], 0, 0, 0);
  }

#pragma unroll
  for (int a = 0; a < 4; ++a)
#pragma unroll
    for (int b = 0; b < 4; ++b) {
      int col = n0 + wc * 64 + b * 16 + lm;  // o = h*64+d
      float bv_ = ldf(bias, col, isf32);
      int h = col >> 6, d = col & 63;
#pragma unroll
      for (int r = 0; r < 4; ++r) {
        int row = m0 + wr * 64 + a * 16 + lq * 4 + r;  // n = b*1024+s
        int bb = row >> 10, s = row & 1023;
        size_t base = ((size_t)(bb * 16 + h)) << 16;
        short o = f2bf(acc[a][b][r] + bv_);
        if (which == 2)      Vt[base + ((size_t)d << 10) + s] = o;
        else if (which == 1) Ko[base + ((size_t)s << 6) + d] = o;
        else                 Qo[base + ((size_t)s << 6) + d] = o;
      }
    }
}

// ------------------------------------------------- k2: scores = Q K^T / 8 (fp16 out)
__global__ __launch_bounds__(256) void k2_scores(
    const short* __restrict__ Q, const short* __restrict__ Kb,
    __half* __restrict__ Sc, int bh0)
{
  __shared__ __align__(16) short As[128 * PITCH];
  __shared__ __align__(16) short Bs[128 * PITCH];
  const int t = threadIdx.x;
  const int m0 = blockIdx.x * 128, n0 = blockIdx.y * 128;
  const int z = blockIdx.z;
  const short* __restrict__ A = Q + ((size_t)(bh0 + z) << 16);
  const short* __restrict__ B = Kb + ((size_t)(bh0 + z) << 16);
  const int lane = t & 63, wvi = t >> 6;
  const int wr = wvi >> 1, wc = wvi & 1;
  const int lm = lane & 15, lq = lane >> 4;
  f32x4 acc[4][4] = {};

  for (int k0 = 0; k0 < 64; k0 += 32) {
    __syncthreads();
#pragma unroll
    for (int i = 0; i < 2; ++i) {
      int l = t + i * 256;
      int row = l >> 2, kk = (l & 3) << 3;
      *(int4*)&As[row * PITCH + kk] = *(const int4*)&A[(size_t)(m0 + row) * 64 + k0 + kk];
      *(int4*)&Bs[row * PITCH + kk] = *(const int4*)&B[(size_t)(n0 + row) * 64 + k0 + kk];
    }
    __syncthreads();
    short8 af[4], bf[4];
#pragma unroll
    for (int a = 0; a < 4; ++a) af[a] = *(const short8*)&As[(wr * 64 + a * 16 + lm) * PITCH + lq * 8];
#pragma unroll
    for (int b = 0; b < 4; ++b) bf[b] = *(const short8*)&Bs[(wc * 64 + b * 16 + lm) * PITCH + lq * 8];
#pragma unroll
    for (int a = 0; a < 4; ++a)
#pragma unroll
      for (int b = 0; b < 4; ++b)
        acc[a][b] = __builtin_amdgcn_mfma_f32_16x16x32_bf16(af[a], bf[b], acc[a][b], 0, 0, 0);
  }

#pragma unroll
  for (int a = 0; a < 4; ++a)
#pragma unroll
    for (int b = 0; b < 4; ++b) {
      int col = n0 + wc * 64 + b * 16 + lm;
#pragma unroll
      for (int r = 0; r < 4; ++r) {
        int row = m0 + wr * 64 + a * 16 + lq * 4 + r;
        Sc[(size_t)z * 1048576 + (size_t)row * 1024 + col] = __float2half(acc[a][b][r] * 0.125f);
      }
    }
}

// ------------------------------------------------- FFT helpers
__device__ __forceinline__ void init_tw(float2* tw, int tid) {
  for (int j = tid; j < 512; j += 256) {
    float a = (float)j * (6.283185307179586f / 1024.0f);
    float s, c;
    __sincosf(a, &s, &c);
    tw[j] = make_float2(c, -s);  // e^{-2*pi*i*j/1024}
  }
}

// Stockham radix-2, 1024-pt, 256 threads, self-sorting; result ends in X.
template <bool INV>
__device__ __forceinline__ void fft1024(float2* X, float2* Y, const float2* tw, int tid) {
  float2* src = X;
  float2* dst = Y;
#pragma unroll
  for (int st = 0; st < 10; ++st) {
    __syncthreads();
    const int Ns = 1 << st;
#pragma unroll
    for (int jj = 0; jj < 2; ++jj) {
      int j = tid + jj * 256;
      int k = j & (Ns - 1);
      float2 a = src[j];
      float2 b = src[j + 512];
      float2 w = tw[k << (9 - st)];
      float wy = INV ? -w.y : w.y;
      float2 bw = make_float2(b.x * w.x - b.y * wy, b.x * wy + b.y * w.x);
      int d0 = ((j >> st) << (st + 1)) | k;
      dst[d0]      = make_float2(a.x + bw.x, a.y + bw.y);
      dst[d0 + Ns] = make_float2(a.x - bw.x, a.y - bw.y);
    }
    float2* tmp = src; src = dst; dst = tmp;
  }
  __syncthreads();
}

// ------------------------------------------------- k3: row FFT (R2C, keep v=0..512)
__global__ __launch_bounds__(256) void k3_rowfft(const __half* __restrict__ Sc,
                                                 __half2* __restrict__ Cbuf)
{
  __shared__ float2 X[1024], Y[1024], tw[512];
  const int tid = threadIdx.x;
  const int q = blockIdx.x, z = blockIdx.y;
  init_tw(tw, tid);
  const __half* row = Sc + ((size_t)z * 1024 + q) * 1024;
  for (int v = tid; v < 1024; v += 256) X[v] = make_float2(__half2float(row[v]), 0.0f);
  fft1024<false>(X, Y, tw, tid);
  __half2* outr = Cbuf + ((size_t)z * 1024 + q) * 513;
  for (int v = tid; v < 513; v += 256) outr[v] = __float22half2_rn(X[v]);
}

// ------------------------------------------------- k4: col DIF-FFT + gain + col iDIT-FFT
// 4 columns/block in LDS; elementwise filter is permutation-invariant so the
// bitrev ordering between DIF and DIT needs no fixup.
__global__ __launch_bounds__(256) void k4_colfft(__half2* __restrict__ Cbuf,
                                                  const int* __restrict__ flags)
{
  __shared__ float2 tile[1024 * 5];
  __shared__ float2 tw[512];
  const int tid = threadIdx.x;
  const int v0 = blockIdx.x * 4;
  const int z = blockIdx.y;
  const float alpha = ((const float*)flags)[1];
  init_tw(tw, tid);
  __half2* base = Cbuf + (size_t)z * 1024 * 513;

  for (int i = tid; i < 4096; i += 256) {
    int q = i >> 2, v = i & 3, gv = v0 + v;
    tile[q * 5 + v] = (gv < 513) ? __half22float2(base[(size_t)q * 513 + gv])
                                 : make_float2(0.f, 0.f);
  }
  // forward DIF (natural -> bitrev), w = e^{-2pi i k/len}
  for (int s = 10; s >= 1; --s) {
    const int half = 1 << (s - 1);
    __syncthreads();
    for (int i = tid; i < 2048; i += 256) {
      int v = i & 3, b = i >> 2;
      int k = b & (half - 1), blk = b >> (s - 1);
      int i0 = (blk << s) | k, i1 = i0 + half;
      float2 x0 = tile[i0 * 5 + v], x1 = tile[i1 * 5 + v];
      float2 w = tw[k << (10 - s)];
      float2 d = make_float2(x0.x - x1.x, x0.y - x1.y);
      tile[i0 * 5 + v] = make_float2(x0.x + x1.x, x0.y + x1.y);
      tile[i1 * 5 + v] = make_float2(d.x * w.x - d.y * w.y, d.x * w.y + d.y * w.x);
    }
  }
  __syncthreads();
  // real spectral gain; fold ifft2's 1/N^2 here
  for (int i = tid; i < 4096; i += 256) {
    int q = i >> 2, v = i & 3;
    float2 f = tile[q * 5 + v];
    float mag = sqrtf(f.x * f.x + f.y * f.y);
    float wf = __cosf(alpha * atanf(__logf(mag + 1e-10f))) * (1.0f / 1048576.0f);
    tile[q * 5 + v] = make_float2(f.x * wf, f.y * wf);
  }
  // inverse DIT (bitrev -> natural), w = e^{+2pi i k/len}
  for (int s = 1; s <= 10; ++s) {
    const int half = 1 << (s - 1);
    __syncthreads();
    for (int i = tid; i < 2048; i += 256) {
      int v = i & 3, b = i >> 2;
      int k = b & (half - 1), blk = b >> (s - 1);
      int i0 = (blk << s) | k, i1 = i0 + half;
      float2 x0 = tile[i0 * 5 + v], x1 = tile[i1 * 5 + v];
      float2 w = tw[k << (10 - s)];
      float2 tt = make_float2(x1.x * w.x + x1.y * w.y, x1.y * w.x - x1.x * w.y); // x1*conj(w)
      tile[i0 * 5 + v] = make_float2(x0.x + tt.x, x0.y + tt.y);
      tile[i1 * 5 + v] = make_float2(x0.x - tt.x, x0.y - tt.y);
    }
  }
  __syncthreads();
  for (int i = tid; i < 4096; i += 256) {
    int q = i >> 2, v = i & 3, gv = v0 + v;
    if (gv < 513) base[(size_t)q * 513 + gv] = __float22half2_rn(tile[q * 5 + v]);
  }
}

// ------------------------------------------------- k5: Hermitian irow-FFT + softmax -> bf16 attn
__global__ __launch_bounds__(256) void k5_softmax(const __half2* __restrict__ Cbuf,
                                                   short* __restrict__ attn)
{
  __shared__ float2 X[1024], Y[1024], tw[512];
  __shared__ float rbuf[256];
  const int tid = threadIdx.x;
  const int q = blockIdx.x, z = blockIdx.y;
  init_tw(tw, tid);
  const __half2* in = Cbuf + ((size_t)z * 1024 + q) * 513;
  for (int v = tid; v < 513; v += 256) X[v] = __half22float2(in[v]);
  __syncthreads();
  for (int v = tid; v < 1024; v += 256)
    if (v >= 513) { float2 m = X[1024 - v]; X[v] = make_float2(m.x, -m.y); }
  fft1024<true>(X, Y, tw, tid);  // 1/N^2 already folded into k4's gain

  float lmx = -3.4e38f;
  for (int v = tid; v < 1024; v += 256) lmx = fmaxf(lmx, X[v].x);
  rbuf[tid] = lmx;
  __syncthreads();
  for (int s = 128; s > 0; s >>= 1) { if (tid < s) rbuf[tid] = fmaxf(rbuf[tid], rbuf[tid + s]); __syncthreads(); }
  const float gmax = rbuf[0];
  __syncthreads();
  float ls = 0.f;
  for (int v = tid; v < 1024; v += 256) { float e = __expf(X[v].x - gmax); Y[v].x = e; ls += e; }
  rbuf[tid] = ls;
  __syncthreads();
  for (int s = 128; s > 0; s >>= 1) { if (tid < s) rbuf[tid] += rbuf[tid + s]; __syncthreads(); }
  const float inv = 1.0f / rbuf[0];
  short* arow = attn + ((size_t)z * 1024 + q) * 1024;
  for (int v = tid; v < 1024; v += 256) arow[v] = f2bf(Y[v].x * inv);
}

// ------------------------------------------------- k6: ctx = attn @ V  (BM=128, BN=64)
__global__ __launch_bounds__(256) void k6_av(
    const short* __restrict__ attn, const short* __restrict__ Vt,
    short* __restrict__ ctx, int bh0)
{
  __shared__ __align__(16) short As[128 * PITCH];
  __shared__ __align__(16) short Bs[64 * PITCH];
  const int t = threadIdx.x;
  const int m0 = blockIdx.x * 128;
  const int z = blockIdx.y;
  const short* __restrict__ A = attn + (size_t)z * 1048576;
  const short* __restrict__ B = Vt + ((size_t)(bh0 + z) << 16);
  const int lane = t & 63, w = t >> 6;
  const int lm = lane & 15, lq = lane >> 4;
  f32x4 acc[2][4] = {};

  for (int k0 = 0; k0 < 1024; k0 += 32) {
    __syncthreads();
#pragma unroll
    for (int i = 0; i < 2; ++i) {
      int l = t + i * 256;
      int row = l >> 2, kk = (l & 3) << 3;
      *(int4*)&As[row * PITCH + kk] = *(const int4*)&A[(size_t)(m0 + row) * 1024 + k0 + kk];
    }
    {
      int row = t >> 2, kk = (t & 3) << 3;
      *(int4*)&Bs[row * PITCH + kk] = *(const int4*)&B[(size_t)row * 1024 + k0 + kk];
    }
    __syncthreads();
    short8 af[2], bf[4];
#pragma unroll
    for (int a = 0; a < 2; ++a) af[a] = *(const short8*)&As[(w * 32 + a * 16 + lm) * PITCH + lq * 8];
#pragma unroll
    for (int b = 0; b < 4; ++b) bf[b] = *(const short8*)&Bs[(b * 16 + lm) * PITCH + lq * 8];
#pragma unroll
    for (int a = 0; a < 2; ++a)
#pragma unroll
      for (int b = 0; b < 4; ++b)
        acc[a][b] = __builtin_amdgcn_mfma_f32_16x16x32_bf16(af[a], bf[b], acc[a][b], 0, 0, 0);
  }

#pragma unroll
  for (int a = 0; a < 2; ++a)
#pragma unroll
    for (int b = 0; b < 4; ++b) {
      int col = b * 16 + lm;
#pragma unroll
      for (int r = 0; r < 4; ++r) {
        int row = m0 + w * 32 + a * 16 + lq * 4 + r;
        ctx[((size_t)(bh0 + z) << 16) + (size_t)row * 64 + col] = f2bf(acc[a][b][r]);
      }
    }
}

// ------------------------------------------------- k7: out = ctx @ Wo^T + bo
__global__ __launch_bounds__(256) void k7_out(
    const short* __restrict__ ctx, const void* __restrict__ Wo,
    const void* __restrict__ bo, void* __restrict__ out,
    const int* __restrict__ flags)
{
  __shared__ __align__(16) short As[128 * PITCH];
  __shared__ __align__(16) short Bs[128 * PITCH];
  const int isf32 = flags[0];
  const int t = threadIdx.x;
  const int m0 = blockIdx.x * 128, n0 = blockIdx.y * 128;
  const int lane = t & 63, wvi = t >> 6;
  const int wr = wvi >> 1, wc = wvi & 1;
  const int lm = lane & 15, lq = lane >> 4;
  f32x4 acc[4][4] = {};

  for (int k0 = 0; k0 < 1024; k0 += 32) {
    __syncthreads();
#pragma unroll
    for (int i = 0; i < 2; ++i) {
      int l = t + i * 256;
      int row = l >> 2, kk = (l & 3) << 3;
      int n = m0 + row, e = k0 + kk;
      // ctx is head-major [bh][s][d]; gather the [n=(b,s)][e=(h,d)] view
      size_t aaddr = (((size_t)((n >> 10) * 16 + (e >> 6))) << 16) + (size_t)((n & 1023) << 6) + (e & 63);
      *(int4*)&As[row * PITCH + kk] = *(const int4*)&ctx[aaddr];
      *(short8*)&Bs[row * PITCH + kk] = ld8(Wo, (size_t)(n0 + row) * 1024 + e, isf32);
    }
    __syncthreads();
    short8 af[4], bf[4];
#pragma unroll
    for (int a = 0; a < 4; ++a) af[a] = *(const short8*)&As[(wr * 64 + a * 16 + lm) * PITCH + lq * 8];
#pragma unroll
    for (int b = 0; b < 4; ++b) bf[b] = *(const short8*)&Bs[(wc * 64 + b * 16 + lm) * PITCH + lq * 8];
#pragma unroll
    for (int a = 0; a < 4; ++a)
#pragma unroll
      for (int b = 0; b < 4; ++b)
        acc[a][b] = __builtin_amdgcn_mfma_f32_16x16x32_bf16(af[a], bf[b], acc[a][b], 0, 0, 0);
  }

#pragma unroll
  for (int a = 0; a < 4; ++a)
#pragma unroll
    for (int b = 0; b < 4; ++b) {
      int col = n0 + wc * 64 + b * 16 + lm;
      float bo_ = ldf(bo, col, isf32);
#pragma unroll
      for (int r = 0; r < 4; ++r) {
        int row = m0 + wr * 64 + a * 16 + lq * 4 + r;
        float v = acc[a][b][r] + bo_;
        size_t oidx = (size_t)row * 1024 + col;
        if (isf32) ((float*)out)[oidx] = v;
        else       ((short*)out)[oidx] = f2bf(v);
      }
    }
}

// ------------------------------------------------- launch
extern "C" void kernel_launch(void* const* d_in, const int* in_sizes, int n_in,
                              void* d_out, int out_size, void* d_ws, size_t ws_size,
                              hipStream_t stream)
{
  const void* x  = d_in[0];
  const void* Wq = d_in[1];
  const void* bq = d_in[2];
  const void* Wk = d_in[3];
  const void* bk = d_in[4];
  const void* Wv = d_in[5];
  const void* bv = d_in[6];
  const void* Wo = d_in[7];
  const void* bo = d_in[8];
  const void* alphap = d_in[9];
  char* ws = (char*)d_ws;

  short*   Q    = (short*)(ws);
  short*   Kb   = (short*)(ws + (size_t)( 8u << 20));
  short*   Vt   = (short*)(ws + (size_t)(16u << 20));
  short*   ctx  = (short*)(ws + (size_t)(24u << 20));
  __half*  Sc   = (__half*)(ws + (size_t)(32u << 20));   // 16 MiB (8 bh chunk)
  short*   attn = (short*)(ws + (size_t)(32u << 20));    // aliases Sc
  __half2* Cbuf = (__half2*)(ws + (size_t)(48u << 20));  // ~16.03 MiB
  int*     flags = (int*)(ws + (size_t)(65u << 20));

  k0_detect<<<1, 256, 0, stream>>>((const unsigned*)x, alphap, flags);
  k1_qkv<<<dim3(32, 8, 3), 256, 0, stream>>>(x, Wq, bq, Wk, bk, Wv, bv, Q, Kb, Vt, flags);
  for (int c = 0; c < 8; ++c) {
    int bh0 = c * 8;
    k2_scores<<<dim3(8, 8, 8), 256, 0, stream>>>(Q, Kb, Sc, bh0);
    k3_rowfft<<<dim3(1024, 8), 256, 0, stream>>>(Sc, Cbuf);
    k4_colfft<<<dim3(129, 8), 256, 0, stream>>>(Cbuf, flags);
    k5_softmax<<<dim3(1024, 8), 256, 0, stream>>>(Cbuf, attn);
    k6_av<<<dim3(8, 8), 256, 0, stream>>>(attn, Vt, ctx, bh0);
  }
  k7_out<<<dim3(32, 8), 256, 0, stream>>>(ctx, Wo, bo, d_out, flags);
}

// Round 3
// 1526.936 us; speedup vs baseline: 1.1257x; 1.1257x over previous
//
#include <hip/hip_runtime.h>
#include <hip/hip_fp16.h>

// SpectralAttention: B=4, S=1024, E=1024, H=16, HD=64.
// Identity: real(ifft2(F*exp(i*phi))) == ifft2(F * cos(phi)) for real scores
// (phi symmetric under (u,v)->(-u,-v)) => real spectral gain, Hermitian
// half-spectrum (v=0..512), no bit-reversal fixups.
//
// Round-3 structure:
//  - Ct stored TRANSPOSED [z][v][q] so the column FFT (k4) is q-contiguous.
//  - k3/k5 use real-FFT pairing: 2 real rows per complex FFT (halves FFT work).
//  - GEMM epilogues bounce through LDS -> coalesced int4 stores.
//
// Workspace (<= 65 MiB + flags):
//   0      Q    bf16 [bh][s][d]     8 MiB
//   8 MiB  Kb   bf16 [bh][s][d]     8 MiB
//   16 MiB Vt   bf16 [bh][d][s]     8 MiB
//   24 MiB ctx  bf16 [bh][s][d]     8 MiB
//   32 MiB Sc   fp16 [8][q][k]     16 MiB  (aliased by attn bf16)
//   48 MiB Ct   half2 [8][513][1024] 16.03 MiB
//   65 MiB flags: [0]=isf32, [1]=alpha(f32)

typedef __attribute__((ext_vector_type(8))) short short8;
typedef __attribute__((ext_vector_type(4))) float f32x4;

#define PITCH 40  // LDS row pitch (bf16 elems) for GEMM staging tiles

__device__ __forceinline__ float bf2f(short v) {
  return __uint_as_float(((unsigned)(unsigned short)v) << 16);
}
__device__ __forceinline__ short f2bf(float f) {
  unsigned u = __float_as_uint(f);
  u += 0x7FFFu + ((u >> 16) & 1u);  // RNE
  return (short)(u >> 16);
}

__device__ __forceinline__ short8 ld8(const void* p, size_t idx, int isf32) {
  short8 r;
  if (isf32) {
    const float* f = (const float*)p + idx;
    float4 a = *(const float4*)f;
    float4 b = *(const float4*)(f + 4);
    r[0] = f2bf(a.x); r[1] = f2bf(a.y); r[2] = f2bf(a.z); r[3] = f2bf(a.w);
    r[4] = f2bf(b.x); r[5] = f2bf(b.y); r[6] = f2bf(b.z); r[7] = f2bf(b.w);
  } else {
    r = *(const short8*)((const short*)p + idx);
  }
  return r;
}
__device__ __forceinline__ float ldf(const void* p, int idx, int isf32) {
  return isf32 ? ((const float*)p)[idx] : bf2f(((const short*)p)[idx]);
}

// ------------------------------------------------- k0: dtype detect + alpha
__global__ void k0_detect(const unsigned* __restrict__ q,
                          const void* __restrict__ alphap, int* __restrict__ flags) {
  __shared__ float smax[256];
  __shared__ int szero[256];
  int t = threadIdx.x;
  float mx = 0.f; int zc = 0;
  for (int i = t; i < 16384; i += 256) {
    unsigned w = q[i];
    unsigned lo = w & 0xFFFFu;
    float v = fabsf(__uint_as_float(lo << 16));
    if (!(v <= 1e30f)) v = 1e30f;
    mx = fmaxf(mx, v);
    zc += (lo == 0u);
  }
  smax[t] = mx; szero[t] = zc;
  __syncthreads();
  for (int s = 128; s > 0; s >>= 1) {
    if (t < s) { smax[t] = fmaxf(smax[t], smax[t + s]); szero[t] += szero[t + s]; }
    __syncthreads();
  }
  if (t == 0) {
    int isf32 = (smax[0] > 100.f) || (szero[0] > 12288);
    flags[0] = isf32;
    float alpha = isf32 ? *(const float*)alphap : bf2f(*(const short*)alphap);
    ((float*)flags)[1] = alpha;
  }
}

// ------------------------------------------------- k1: QKV projection
__global__ __launch_bounds__(256) void k1_qkv(
    const void* __restrict__ x,
    const void* __restrict__ Wq, const void* __restrict__ bq,
    const void* __restrict__ Wk, const void* __restrict__ bk,
    const void* __restrict__ Wv, const void* __restrict__ bv,
    short* __restrict__ Qo, short* __restrict__ Ko, short* __restrict__ Vt,
    const int* __restrict__ flags)
{
  __shared__ __align__(16) char smem[128 * 136 * 2];  // union: As+Bs | Ct
  short* As = (short*)smem;
  short* Bs = As + 128 * PITCH;
  short* Ct = (short*)smem;  // 128 x 136 bf16
  const int isf32 = flags[0];
  const int t = threadIdx.x;
  const int m0 = blockIdx.x * 128, n0 = blockIdx.y * 128;
  const int which = blockIdx.z;
  const void* __restrict__ W = (which == 0) ? Wq : (which == 1) ? Wk : Wv;
  const void* __restrict__ bias = (which == 0) ? bq : (which == 1) ? bk : bv;
  const int lane = t & 63, wvi = t >> 6;
  const int wr = wvi >> 1, wc = wvi & 1;
  const int lm = lane & 15, lq = lane >> 4;
  f32x4 acc[4][4] = {};

  for (int k0 = 0; k0 < 1024; k0 += 32) {
    __syncthreads();
#pragma unroll
    for (int i = 0; i < 2; ++i) {
      int l = t + i * 256;
      int row = l >> 2, kk = (l & 3) << 3;
      *(short8*)&As[row * PITCH + kk] = ld8(x, (size_t)(m0 + row) * 1024 + k0 + kk, isf32);
      *(short8*)&Bs[row * PITCH + kk] = ld8(W, (size_t)(n0 + row) * 1024 + k0 + kk, isf32);
    }
    __syncthreads();
    short8 af[4], bf[4];
#pragma unroll
    for (int a = 0; a < 4; ++a) af[a] = *(const short8*)&As[(wr * 64 + a * 16 + lm) * PITCH + lq * 8];
#pragma unroll
    for (int b = 0; b < 4; ++b) bf[b] = *(const short8*)&Bs[(wc * 64 + b * 16 + lm) * PITCH + lq * 8];
#pragma unroll
    for (int a = 0; a < 4; ++a)
#pragma unroll
      for (int b = 0; b < 4; ++b)
        acc[a][b] = __builtin_amdgcn_mfma_f32_16x16x32_bf16(af[a], bf[b], acc[a][b], 0, 0, 0);
  }

  __syncthreads();  // As/Bs reads done; reuse as Ct
#pragma unroll
  for (int a = 0; a < 4; ++a)
#pragma unroll
    for (int b = 0; b < 4; ++b) {
      int col = wc * 64 + b * 16 + lm;
      float bv_ = ldf(bias, n0 + col, isf32);
#pragma unroll
      for (int r = 0; r < 4; ++r) {
        int row = wr * 64 + a * 16 + lq * 4 + r;
        Ct[row * 136 + col] = f2bf(acc[a][b][r] + bv_);
      }
    }
  __syncthreads();

  if (which != 2) {
    // Q/K: [bh][s][d] row-major; 2048 int4 tiles
    short* __restrict__ O = (which == 1) ? Ko : Qo;
#pragma unroll
    for (int j = 0; j < 8; ++j) {
      int id = t + j * 256;
      int row = id >> 4, c16 = (id & 15) * 8;
      short8 v = *(const short8*)&Ct[row * 136 + c16];
      int col = n0 + c16;
      int h = col >> 6, d = col & 63;
      int n = m0 + row, bb = n >> 10, s = n & 1023;
      *(short8*)&O[(((size_t)(bb * 16 + h)) << 16) + ((size_t)s << 6) + d] = v;
    }
  } else {
    // V transposed: Vt[bh][d][s]
#pragma unroll
    for (int j = 0; j < 8; ++j) {
      int id = t + j * 256;
      int d128 = id & 127, sg = (id >> 7) * 8;
      short vals[8];
#pragma unroll
      for (int i = 0; i < 8; ++i) vals[i] = Ct[(sg + i) * 136 + d128];
      int col = n0 + d128;
      int h = col >> 6, d = col & 63;
      int bb = m0 >> 10, sbase = (m0 & 1023) + sg;
      *(short8*)&Vt[(((size_t)(bb * 16 + h)) << 16) + ((size_t)d << 10) + sbase] = *(short8*)vals;
    }
  }
}

// ------------------------------------------------- k2: scores = Q K^T / 8 (fp16)
__global__ __launch_bounds__(256) void k2_scores(
    const short* __restrict__ Q, const short* __restrict__ Kb,
    __half* __restrict__ Sc, int bh0)
{
  __shared__ __align__(16) char smem[128 * 136 * 2];
  short* As = (short*)smem;
  short* Bs = As + 128 * PITCH;
  __half* Ct = (__half*)smem;
  const int t = threadIdx.x;
  const int m0 = blockIdx.x * 128, n0 = blockIdx.y * 128;
  const int z = blockIdx.z;
  const short* __restrict__ A = Q + ((size_t)(bh0 + z) << 16);
  const short* __restrict__ B = Kb + ((size_t)(bh0 + z) << 16);
  const int lane = t & 63, wvi = t >> 6;
  const int wr = wvi >> 1, wc = wvi & 1;
  const int lm = lane & 15, lq = lane >> 4;
  f32x4 acc[4][4] = {};

  for (int k0 = 0; k0 < 64; k0 += 32) {
    __syncthreads();
#pragma unroll
    for (int i = 0; i < 2; ++i) {
      int l = t + i * 256;
      int row = l >> 2, kk = (l & 3) << 3;
      *(int4*)&As[row * PITCH + kk] = *(const int4*)&A[(size_t)(m0 + row) * 64 + k0 + kk];
      *(int4*)&Bs[row * PITCH + kk] = *(const int4*)&B[(size_t)(n0 + row) * 64 + k0 + kk];
    }
    __syncthreads();
    short8 af[4], bf[4];
#pragma unroll
    for (int a = 0; a < 4; ++a) af[a] = *(const short8*)&As[(wr * 64 + a * 16 + lm) * PITCH + lq * 8];
#pragma unroll
    for (int b = 0; b < 4; ++b) bf[b] = *(const short8*)&Bs[(wc * 64 + b * 16 + lm) * PITCH + lq * 8];
#pragma unroll
    for (int a = 0; a < 4; ++a)
#pragma unroll
      for (int b = 0; b < 4; ++b)
        acc[a][b] = __builtin_amdgcn_mfma_f32_16x16x32_bf16(af[a], bf[b], acc[a][b], 0, 0, 0);
  }

  __syncthreads();
#pragma unroll
  for (int a = 0; a < 4; ++a)
#pragma unroll
    for (int b = 0; b < 4; ++b) {
      int col = wc * 64 + b * 16 + lm;
#pragma unroll
      for (int r = 0; r < 4; ++r) {
        int row = wr * 64 + a * 16 + lq * 4 + r;
        Ct[row * 136 + col] = __float2half(acc[a][b][r] * 0.125f);
      }
    }
  __syncthreads();
#pragma unroll
  for (int j = 0; j < 8; ++j) {
    int id = t + j * 256;
    int row = id >> 4, c16 = (id & 15) * 8;
    int4 v = *(const int4*)&Ct[row * 136 + c16];
    *(int4*)&Sc[(size_t)z * 1048576 + (size_t)(m0 + row) * 1024 + n0 + c16] = v;
  }
}

// ------------------------------------------------- FFT helpers
__device__ __forceinline__ void init_tw(float2* tw, int tid) {
  for (int j = tid; j < 512; j += 256) {
    float a = (float)j * (6.283185307179586f / 1024.0f);
    float s, c;
    __sincosf(a, &s, &c);
    tw[j] = make_float2(c, -s);  // e^{-2*pi*i*j/1024}
  }
}

template <bool INV>
__device__ __forceinline__ void fft1024(float2* X, float2* Y, const float2* tw, int tid) {
  float2* src = X;
  float2* dst = Y;
#pragma unroll
  for (int st = 0; st < 10; ++st) {
    __syncthreads();
    const int Ns = 1 << st;
#pragma unroll
    for (int jj = 0; jj < 2; ++jj) {
      int j = tid + jj * 256;
      int k = j & (Ns - 1);
      float2 a = src[j];
      float2 b = src[j + 512];
      float2 w = tw[k << (9 - st)];
      float wy = INV ? -w.y : w.y;
      float2 bw = make_float2(b.x * w.x - b.y * wy, b.x * wy + b.y * w.x);
      int d0 = ((j >> st) << (st + 1)) | k;
      dst[d0]      = make_float2(a.x + bw.x, a.y + bw.y);
      dst[d0 + Ns] = make_float2(a.x - bw.x, a.y - bw.y);
    }
    float2* tmp = src; src = dst; dst = tmp;
  }
  __syncthreads();
}

// ------------------------------------------------- k3: paired row FFT -> Ct[v][q]
// Block: 16 rows (8 paired complex FFTs). Writes transposed, 16B granules.
__global__ __launch_bounds__(256) void k3_rowfft(const __half* __restrict__ Sc,
                                                 __half2* __restrict__ Ct)
{
  __shared__ float2 X[1024], Y[1024], tw[512];
  __shared__ __half2 Fbuf[16 * 513];
  const int tid = threadIdx.x;
  const int q0 = blockIdx.x * 16, z = blockIdx.y;
  init_tw(tw, tid);
#pragma unroll 1
  for (int r = 0; r < 8; ++r) {
    const __half* r1 = Sc + ((size_t)z * 1024 + q0 + 2 * r) * 1024;
    const __half* r2 = r1 + 1024;
    __syncthreads();  // protect X from prior unpack reads
    for (int v = tid; v < 1024; v += 256)
      X[v] = make_float2(__half2float(r1[v]), __half2float(r2[v]));
    fft1024<false>(X, Y, tw, tid);
    for (int v = tid; v < 513; v += 256) {
      int w = (1024 - v) & 1023;
      float2 A = X[v], B = X[w];
      // F1 = (Z + conj(Z~))/2 ; F2 = (Z - conj(Z~))/(2i)
      Fbuf[(2 * r) * 513 + v]     = __float22half2_rn(make_float2((A.x + B.x) * 0.5f, (A.y - B.y) * 0.5f));
      Fbuf[(2 * r + 1) * 513 + v] = __float22half2_rn(make_float2((A.y + B.y) * 0.5f, (B.x - A.x) * 0.5f));
    }
  }
  __syncthreads();
  __half2* out = Ct + (size_t)z * 513 * 1024;
  for (int id = tid; id < 2052; id += 256) {
    int v = id >> 2, qq = (id & 3) * 4;
    int4 o;
    __half2* op = (__half2*)&o;
#pragma unroll
    for (int i = 0; i < 4; ++i) op[i] = Fbuf[(qq + i) * 513 + v];
    *(int4*)&out[(size_t)v * 1024 + q0 + qq] = o;
  }
}

// ------------------------------------------------- k4: column FFT + gain + iFFT
// Block: 4 v-rows of Ct (each 1024 q, contiguous). fp32 LDS tile.
__global__ __launch_bounds__(256) void k4_colfft(__half2* __restrict__ Ct,
                                                  const int* __restrict__ flags)
{
  __shared__ float2 tile[4 * 1024];
  __shared__ float2 tw[512];
  const int tid = threadIdx.x;
  const int v0 = blockIdx.x * 4;
  const int z = blockIdx.y;
  const float alpha = ((const float*)flags)[1];
  init_tw(tw, tid);
  __half2* base = Ct + (size_t)z * 513 * 1024;

  for (int i = tid; i < 4096; i += 256) {
    int c = i >> 10, q = i & 1023, gv = v0 + c;
    tile[i] = (gv < 513) ? __half22float2(base[(size_t)gv * 1024 + q]) : make_float2(0.f, 0.f);
  }
  // forward DIF over q (natural -> bitrev)
  for (int s = 10; s >= 1; --s) {
    const int half = 1 << (s - 1);
    __syncthreads();
    for (int i = tid; i < 2048; i += 256) {
      int c = i >> 9, b = i & 511;
      int k = b & (half - 1), blk = b >> (s - 1);
      int i0 = (c << 10) | (blk << s) | k, i1 = i0 + half;
      float2 x0 = tile[i0], x1 = tile[i1];
      float2 w = tw[k << (10 - s)];
      float2 d = make_float2(x0.x - x1.x, x0.y - x1.y);
      tile[i0] = make_float2(x0.x + x1.x, x0.y + x1.y);
      tile[i1] = make_float2(d.x * w.x - d.y * w.y, d.x * w.y + d.y * w.x);
    }
  }
  __syncthreads();
  // real spectral gain, with ifft2's 1/N^2 folded in
  for (int i = tid; i < 4096; i += 256) {
    float2 f = tile[i];
    float mag = sqrtf(f.x * f.x + f.y * f.y);
    float wf = __cosf(alpha * atanf(__logf(mag + 1e-10f))) * (1.0f / 1048576.0f);
    tile[i] = make_float2(f.x * wf, f.y * wf);
  }
  // inverse DIT over q (bitrev -> natural)
  for (int s = 1; s <= 10; ++s) {
    const int half = 1 << (s - 1);
    __syncthreads();
    for (int i = tid; i < 2048; i += 256) {
      int c = i >> 9, b = i & 511;
      int k = b & (half - 1), blk = b >> (s - 1);
      int i0 = (c << 10) | (blk << s) | k, i1 = i0 + half;
      float2 x0 = tile[i0], x1 = tile[i1];
      float2 w = tw[k << (10 - s)];
      float2 tt = make_float2(x1.x * w.x + x1.y * w.y, x1.y * w.x - x1.x * w.y);  // x1*conj(w)
      tile[i0] = make_float2(x0.x + tt.x, x0.y + tt.y);
      tile[i1] = make_float2(x0.x - tt.x, x0.y - tt.y);
    }
  }
  __syncthreads();
  for (int i = tid; i < 4096; i += 256) {
    int c = i >> 10, q = i & 1023, gv = v0 + c;
    if (gv < 513) base[(size_t)gv * 1024 + q] = __float22half2_rn(tile[i]);
  }
}

// ------------------------------------------------- k5: paired inverse row FFT + softmax
__global__ __launch_bounds__(256) void k5_softmax(const __half2* __restrict__ Ct,
                                                   short* __restrict__ attn)
{
  __shared__ float2 X[1024], Y[1024], tw[512];
  __shared__ __half2 Gbuf[16 * 513];
  __shared__ float2 rbuf[4];
  const int tid = threadIdx.x;
  const int q0 = blockIdx.x * 16, z = blockIdx.y;
  const int lane = tid & 63, wv = tid >> 6;
  init_tw(tw, tid);
  const __half2* in = Ct + (size_t)z * 513 * 1024;
  for (int id = tid; id < 2052; id += 256) {
    int v = id >> 2, qq = (id & 3) * 4;
    int4 o = *(const int4*)&in[(size_t)v * 1024 + q0 + qq];
    __half2* op = (__half2*)&o;
#pragma unroll
    for (int i = 0; i < 4; ++i) Gbuf[(qq + i) * 513 + v] = op[i];
  }
#pragma unroll 1
  for (int r = 0; r < 8; ++r) {
    __syncthreads();  // Gbuf ready (r=0) / X free (r>0)
    for (int v = tid; v < 1024; v += 256) {
      float2 g1, g2;
      if (v <= 512) {
        g1 = __half22float2(Gbuf[(2 * r) * 513 + v]);
        g2 = __half22float2(Gbuf[(2 * r + 1) * 513 + v]);
      } else {
        int w = 1024 - v;
        float2 a = __half22float2(Gbuf[(2 * r) * 513 + w]);
        float2 b = __half22float2(Gbuf[(2 * r + 1) * 513 + w]);
        g1 = make_float2(a.x, -a.y);
        g2 = make_float2(b.x, -b.y);
      }
      X[v] = make_float2(g1.x - g2.y, g1.y + g2.x);  // G1 + i*G2
    }
    fft1024<true>(X, Y, tw, tid);  // Re = row 2r, Im = row 2r+1

    // dual-row softmax
    float m1 = -3.4e38f, m2 = -3.4e38f;
    for (int v = tid; v < 1024; v += 256) { m1 = fmaxf(m1, X[v].x); m2 = fmaxf(m2, X[v].y); }
#pragma unroll
    for (int s = 32; s > 0; s >>= 1) {
      m1 = fmaxf(m1, __shfl_xor(m1, s, 64));
      m2 = fmaxf(m2, __shfl_xor(m2, s, 64));
    }
    if (lane == 0) rbuf[wv] = make_float2(m1, m2);
    __syncthreads();
    float gm1 = fmaxf(fmaxf(rbuf[0].x, rbuf[1].x), fmaxf(rbuf[2].x, rbuf[3].x));
    float gm2 = fmaxf(fmaxf(rbuf[0].y, rbuf[1].y), fmaxf(rbuf[2].y, rbuf[3].y));
    __syncthreads();
    float s1 = 0.f, s2 = 0.f;
    for (int v = tid; v < 1024; v += 256) {
      float e1 = __expf(X[v].x - gm1), e2 = __expf(X[v].y - gm2);
      Y[v] = make_float2(e1, e2);
      s1 += e1; s2 += e2;
    }
#pragma unroll
    for (int s = 32; s > 0; s >>= 1) {
      s1 += __shfl_xor(s1, s, 64);
      s2 += __shfl_xor(s2, s, 64);
    }
    if (lane == 0) rbuf[wv] = make_float2(s1, s2);
    __syncthreads();
    float inv1 = 1.0f / (rbuf[0].x + rbuf[1].x + rbuf[2].x + rbuf[3].x);
    float inv2 = 1.0f / (rbuf[0].y + rbuf[1].y + rbuf[2].y + rbuf[3].y);
    __syncthreads();
    short* a1 = attn + ((size_t)z * 1024 + q0 + 2 * r) * 1024;
    short* a2 = a1 + 1024;
    for (int v = tid; v < 1024; v += 256) {
      a1[v] = f2bf(Y[v].x * inv1);
      a2[v] = f2bf(Y[v].y * inv2);
    }
  }
}

// ------------------------------------------------- k6: ctx = attn @ V (BM=64, BN=64)
__global__ __launch_bounds__(256) void k6_av(
    const short* __restrict__ attn, const short* __restrict__ Vt,
    short* __restrict__ ctx, int bh0)
{
  __shared__ __align__(16) char smem[2 * 64 * PITCH * 2];  // As+Bs (10240B) | Ct (9216B)
  short* As = (short*)smem;
  short* Bs = As + 64 * PITCH;
  short* Ct = (short*)smem;  // 64 x 72
  const int t = threadIdx.x;
  const int m0 = blockIdx.x * 64;
  const int z = blockIdx.y;
  const short* __restrict__ A = attn + (size_t)z * 1048576;
  const short* __restrict__ B = Vt + ((size_t)(bh0 + z) << 16);
  const int lane = t & 63, w = t >> 6;
  const int lm = lane & 15, lq = lane >> 4;
  f32x4 acc[4] = {};

  for (int k0 = 0; k0 < 1024; k0 += 32) {
    __syncthreads();
    {
      int row = t >> 2, kk = (t & 3) << 3;
      *(int4*)&As[row * PITCH + kk] = *(const int4*)&A[(size_t)(m0 + row) * 1024 + k0 + kk];
      *(int4*)&Bs[row * PITCH + kk] = *(const int4*)&B[(size_t)row * 1024 + k0 + kk];
    }
    __syncthreads();
    short8 af = *(const short8*)&As[(w * 16 + lm) * PITCH + lq * 8];
    short8 bf[4];
#pragma unroll
    for (int b = 0; b < 4; ++b) bf[b] = *(const short8*)&Bs[(b * 16 + lm) * PITCH + lq * 8];
#pragma unroll
    for (int b = 0; b < 4; ++b)
      acc[b] = __builtin_amdgcn_mfma_f32_16x16x32_bf16(af, bf[b], acc[b], 0, 0, 0);
  }

  __syncthreads();
#pragma unroll
  for (int b = 0; b < 4; ++b) {
    int col = b * 16 + lm;
#pragma unroll
    for (int r = 0; r < 4; ++r) {
      int row = w * 16 + lq * 4 + r;
      Ct[row * 72 + col] = f2bf(acc[b][r]);
    }
  }
  __syncthreads();
#pragma unroll
  for (int j = 0; j < 2; ++j) {
    int id = t + j * 256;
    int row = id >> 3, c8 = (id & 7) * 8;
    int4 v = *(const int4*)&Ct[row * 72 + c8];
    *(int4*)&ctx[((size_t)(bh0 + z) << 16) + (size_t)(m0 + row) * 64 + c8] = v;
  }
}

// ------------------------------------------------- k7: out = ctx @ Wo^T + bo
__global__ __launch_bounds__(256) void k7_out(
    const short* __restrict__ ctx, const void* __restrict__ Wo,
    const void* __restrict__ bo, void* __restrict__ out,
    const int* __restrict__ flags)
{
  __shared__ __align__(16) char smem[128 * 136 * 2];
  short* As = (short*)smem;
  short* Bs = As + 128 * PITCH;
  short* Ct = (short*)smem;
  const int isf32 = flags[0];
  const int t = threadIdx.x;
  const int m0 = blockIdx.x * 128, n0 = blockIdx.y * 128;
  const int lane = t & 63, wvi = t >> 6;
  const int wr = wvi >> 1, wc = wvi & 1;
  const int lm = lane & 15, lq = lane >> 4;
  f32x4 acc[4][4] = {};

  for (int k0 = 0; k0 < 1024; k0 += 32) {
    __syncthreads();
#pragma unroll
    for (int i = 0; i < 2; ++i) {
      int l = t + i * 256;
      int row = l >> 2, kk = (l & 3) << 3;
      int n = m0 + row, e = k0 + kk;
      size_t aaddr = (((size_t)((n >> 10) * 16 + (e >> 6))) << 16) + (size_t)((n & 1023) << 6) + (e & 63);
      *(int4*)&As[row * PITCH + kk] = *(const int4*)&ctx[aaddr];
      *(short8*)&Bs[row * PITCH + kk] = ld8(Wo, (size_t)(n0 + row) * 1024 + e, isf32);
    }
    __syncthreads();
    short8 af[4], bf[4];
#pragma unroll
    for (int a = 0; a < 4; ++a) af[a] = *(const short8*)&As[(wr * 64 + a * 16 + lm) * PITCH + lq * 8];
#pragma unroll
    for (int b = 0; b < 4; ++b) bf[b] = *(const short8*)&Bs[(wc * 64 + b * 16 + lm) * PITCH + lq * 8];
#pragma unroll
    for (int a = 0; a < 4; ++a)
#pragma unroll
      for (int b = 0; b < 4; ++b)
        acc[a][b] = __builtin_amdgcn_mfma_f32_16x16x32_bf16(af[a], bf[b], acc[a][b], 0, 0, 0);
  }

  if (isf32) {
#pragma unroll
    for (int a = 0; a < 4; ++a)
#pragma unroll
      for (int b = 0; b < 4; ++b) {
        int col = n0 + wc * 64 + b * 16 + lm;
        float bo_ = ldf(bo, col, 1);
#pragma unroll
        for (int r = 0; r < 4; ++r) {
          int row = m0 + wr * 64 + a * 16 + lq * 4 + r;
          ((float*)out)[(size_t)row * 1024 + col] = acc[a][b][r] + bo_;
        }
      }
    return;
  }
  __syncthreads();
#pragma unroll
  for (int a = 0; a < 4; ++a)
#pragma unroll
    for (int b = 0; b < 4; ++b) {
      int col = wc * 64 + b * 16 + lm;
      float bo_ = ldf(bo, n0 + col, 0);
#pragma unroll
      for (int r = 0; r < 4; ++r) {
        int row = wr * 64 + a * 16 + lq * 4 + r;
        Ct[row * 136 + col] = f2bf(acc[a][b][r] + bo_);
      }
    }
  __syncthreads();
#pragma unroll
  for (int j = 0; j < 8; ++j) {
    int id = t + j * 256;
    int row = id >> 4, c16 = (id & 15) * 8;
    short8 v = *(const short8*)&Ct[row * 136 + c16];
    *(short8*)&((short*)out)[(size_t)(m0 + row) * 1024 + n0 + c16] = v;
  }
}

// ------------------------------------------------- launch
extern "C" void kernel_launch(void* const* d_in, const int* in_sizes, int n_in,
                              void* d_out, int out_size, void* d_ws, size_t ws_size,
                              hipStream_t stream)
{
  const void* x  = d_in[0];
  const void* Wq = d_in[1];
  const void* bq = d_in[2];
  const void* Wk = d_in[3];
  const void* bk = d_in[4];
  const void* Wv = d_in[5];
  const void* bv = d_in[6];
  const void* Wo = d_in[7];
  const void* bo = d_in[8];
  const void* alphap = d_in[9];
  char* ws = (char*)d_ws;

  short*   Q    = (short*)(ws);
  short*   Kb   = (short*)(ws + (size_t)( 8u << 20));
  short*   Vt   = (short*)(ws + (size_t)(16u << 20));
  short*   ctx  = (short*)(ws + (size_t)(24u << 20));
  __half*  Sc   = (__half*)(ws + (size_t)(32u << 20));
  short*   attn = (short*)(ws + (size_t)(32u << 20));  // aliases Sc
  __half2* Ct   = (__half2*)(ws + (size_t)(48u << 20));
  int*     flags = (int*)(ws + (size_t)(65u << 20));

  k0_detect<<<1, 256, 0, stream>>>((const unsigned*)x, alphap, flags);
  k1_qkv<<<dim3(32, 8, 3), 256, 0, stream>>>(x, Wq, bq, Wk, bk, Wv, bv, Q, Kb, Vt, flags);
  for (int c = 0; c < 8; ++c) {
    int bh0 = c * 8;
    k2_scores<<<dim3(8, 8, 8), 256, 0, stream>>>(Q, Kb, Sc, bh0);
    k3_rowfft<<<dim3(64, 8), 256, 0, stream>>>(Sc, Ct);
    k4_colfft<<<dim3(129, 8), 256, 0, stream>>>(Ct, flags);
    k5_softmax<<<dim3(64, 8), 256, 0, stream>>>(Ct, attn);
    k6_av<<<dim3(16, 8), 256, 0, stream>>>(attn, Vt, ctx, bh0);
  }
  k7_out<<<dim3(32, 8), 256, 0, stream>>>(ctx, Wo, bo, d_out, flags);
}

// Round 4
// 1290.805 us; speedup vs baseline: 1.3316x; 1.1829x over previous
//
#include <hip/hip_runtime.h>
#include <hip/hip_fp16.h>

// SpectralAttention: B=4, S=1024, E=1024, H=16, HD=64.
// Identity: real(ifft2(F*exp(i*phi))) == ifft2(F * cos(phi)) for real scores
// (phi symmetric under (u,v)->(-u,-v)) => real spectral gain, Hermitian
// half-spectrum (v=0..512), no bit-reversal fixups.
//
// Round-4 structure:
//  - k23: scores (MFMA regs) -> paired row FFT, fused; Sc buffer deleted.
//  - k56: paired inverse row FFT + softmax -> PV GEMM, fused; attn deleted.
//  - k1/k7: XCD-aware block swizzle (xcd = lb&7 owns 4 m-tiles) for L2 reuse.
//  - chunks of 16 heads; 15 launches total.
//
// Workspace (~64.1 MiB):
//   0      Q    bf16 [bh][s][d]     8 MiB
//   8 MiB  Kb   bf16 [bh][s][d]     8 MiB
//   16 MiB Vt   bf16 [bh][d][s]     8 MiB
//   24 MiB ctx  bf16 [bh][s][d]     8 MiB
//   32 MiB Ct   half2 [16][513][1024]  32.06 MiB  (transposed half-spectrum)
//   +end   flags: [0]=isf32, [1]=alpha(f32)

typedef __attribute__((ext_vector_type(8))) short short8;
typedef __attribute__((ext_vector_type(4))) float f32x4;

#define PITCH 40  // LDS row pitch (bf16 elems) for k1/k7 staging tiles

__device__ __forceinline__ float bf2f(short v) {
  return __uint_as_float(((unsigned)(unsigned short)v) << 16);
}
__device__ __forceinline__ short f2bf(float f) {
  unsigned u = __float_as_uint(f);
  u += 0x7FFFu + ((u >> 16) & 1u);  // RNE
  return (short)(u >> 16);
}

__device__ __forceinline__ short8 ld8(const void* p, size_t idx, int isf32) {
  short8 r;
  if (isf32) {
    const float* f = (const float*)p + idx;
    float4 a = *(const float4*)f;
    float4 b = *(const float4*)(f + 4);
    r[0] = f2bf(a.x); r[1] = f2bf(a.y); r[2] = f2bf(a.z); r[3] = f2bf(a.w);
    r[4] = f2bf(b.x); r[5] = f2bf(b.y); r[6] = f2bf(b.z); r[7] = f2bf(b.w);
  } else {
    r = *(const short8*)((const short*)p + idx);
  }
  return r;
}
__device__ __forceinline__ float ldf(const void* p, int idx, int isf32) {
  return isf32 ? ((const float*)p)[idx] : bf2f(((const short*)p)[idx]);
}

// ------------------------------------------------- k0: dtype detect + alpha
__global__ void k0_detect(const unsigned* __restrict__ q,
                          const void* __restrict__ alphap, int* __restrict__ flags) {
  __shared__ float smax[256];
  __shared__ int szero[256];
  int t = threadIdx.x;
  float mx = 0.f; int zc = 0;
  for (int i = t; i < 16384; i += 256) {
    unsigned w = q[i];
    unsigned lo = w & 0xFFFFu;
    float v = fabsf(__uint_as_float(lo << 16));
    if (!(v <= 1e30f)) v = 1e30f;
    mx = fmaxf(mx, v);
    zc += (lo == 0u);
  }
  smax[t] = mx; szero[t] = zc;
  __syncthreads();
  for (int s = 128; s > 0; s >>= 1) {
    if (t < s) { smax[t] = fmaxf(smax[t], smax[t + s]); szero[t] += szero[t + s]; }
    __syncthreads();
  }
  if (t == 0) {
    int isf32 = (smax[0] > 100.f) || (szero[0] > 12288);
    flags[0] = isf32;
    float alpha = isf32 ? *(const float*)alphap : bf2f(*(const short*)alphap);
    ((float*)flags)[1] = alpha;
  }
}

// ------------------------------------------------- k1: QKV projection (XCD-swizzled)
__global__ __launch_bounds__(256) void k1_qkv(
    const void* __restrict__ x,
    const void* __restrict__ Wq, const void* __restrict__ bq,
    const void* __restrict__ Wk, const void* __restrict__ bk,
    const void* __restrict__ Wv, const void* __restrict__ bv,
    short* __restrict__ Qo, short* __restrict__ Ko, short* __restrict__ Vt,
    const int* __restrict__ flags)
{
  __shared__ __align__(16) char smem[128 * 136 * 2];  // union: As+Bs | Ct
  short* As = (short*)smem;
  short* Bs = As + 128 * PITCH;
  short* Ct = (short*)smem;  // 128 x 136 bf16
  const int isf32 = flags[0];
  const int t = threadIdx.x;
  // XCD swizzle: lb&7 = XCD; each XCD owns m-tiles xcd*4..xcd*4+3, all n-tiles.
  const int lb = blockIdx.x;
  const int m0 = ((lb & 7) * 4 + ((lb >> 3) & 3)) * 128;
  const int n0 = (lb >> 5) * 128;
  const int which = blockIdx.y;
  const void* __restrict__ W = (which == 0) ? Wq : (which == 1) ? Wk : Wv;
  const void* __restrict__ bias = (which == 0) ? bq : (which == 1) ? bk : bv;
  const int lane = t & 63, wvi = t >> 6;
  const int wr = wvi >> 1, wc = wvi & 1;
  const int lm = lane & 15, lq = lane >> 4;
  f32x4 acc[4][4] = {};

  for (int k0 = 0; k0 < 1024; k0 += 32) {
    __syncthreads();
#pragma unroll
    for (int i = 0; i < 2; ++i) {
      int l = t + i * 256;
      int row = l >> 2, kk = (l & 3) << 3;
      *(short8*)&As[row * PITCH + kk] = ld8(x, (size_t)(m0 + row) * 1024 + k0 + kk, isf32);
      *(short8*)&Bs[row * PITCH + kk] = ld8(W, (size_t)(n0 + row) * 1024 + k0 + kk, isf32);
    }
    __syncthreads();
    short8 af[4], bf[4];
#pragma unroll
    for (int a = 0; a < 4; ++a) af[a] = *(const short8*)&As[(wr * 64 + a * 16 + lm) * PITCH + lq * 8];
#pragma unroll
    for (int b = 0; b < 4; ++b) bf[b] = *(const short8*)&Bs[(wc * 64 + b * 16 + lm) * PITCH + lq * 8];
#pragma unroll
    for (int a = 0; a < 4; ++a)
#pragma unroll
      for (int b = 0; b < 4; ++b)
        acc[a][b] = __builtin_amdgcn_mfma_f32_16x16x32_bf16(af[a], bf[b], acc[a][b], 0, 0, 0);
  }

  __syncthreads();  // As/Bs reads done; reuse as Ct
#pragma unroll
  for (int a = 0; a < 4; ++a)
#pragma unroll
    for (int b = 0; b < 4; ++b) {
      int col = wc * 64 + b * 16 + lm;
      float bv_ = ldf(bias, n0 + col, isf32);
#pragma unroll
      for (int r = 0; r < 4; ++r) {
        int row = wr * 64 + a * 16 + lq * 4 + r;
        Ct[row * 136 + col] = f2bf(acc[a][b][r] + bv_);
      }
    }
  __syncthreads();

  if (which != 2) {
    short* __restrict__ O = (which == 1) ? Ko : Qo;
#pragma unroll
    for (int j = 0; j < 8; ++j) {
      int id = t + j * 256;
      int row = id >> 4, c16 = (id & 15) * 8;
      short8 v = *(const short8*)&Ct[row * 136 + c16];
      int col = n0 + c16;
      int h = col >> 6, d = col & 63;
      int n = m0 + row, bb = n >> 10, s = n & 1023;
      *(short8*)&O[(((size_t)(bb * 16 + h)) << 16) + ((size_t)s << 6) + d] = v;
    }
  } else {
#pragma unroll
    for (int j = 0; j < 8; ++j) {
      int id = t + j * 256;
      int d128 = id & 127, sg = (id >> 7) * 8;
      short vals[8];
#pragma unroll
      for (int i = 0; i < 8; ++i) vals[i] = Ct[(sg + i) * 136 + d128];
      int col = n0 + d128;
      int h = col >> 6, d = col & 63;
      int bb = m0 >> 10, sbase = (m0 & 1023) + sg;
      *(short8*)&Vt[(((size_t)(bb * 16 + h)) << 16) + ((size_t)d << 10) + sbase] = *(short8*)vals;
    }
  }
}

// ------------------------------------------------- FFT helpers
__device__ __forceinline__ void init_tw(float2* tw, int tid) {
  for (int j = tid; j < 512; j += 256) {
    float a = (float)j * (6.283185307179586f / 1024.0f);
    float s, c;
    __sincosf(a, &s, &c);
    tw[j] = make_float2(c, -s);  // e^{-2*pi*i*j/1024}
  }
}

template <bool INV>
__device__ __forceinline__ void fft1024(float2* X, float2* Y, const float2* tw, int tid) {
  float2* src = X;
  float2* dst = Y;
#pragma unroll
  for (int st = 0; st < 10; ++st) {
    __syncthreads();
    const int Ns = 1 << st;
#pragma unroll
    for (int jj = 0; jj < 2; ++jj) {
      int j = tid + jj * 256;
      int k = j & (Ns - 1);
      float2 a = src[j];
      float2 b = src[j + 512];
      float2 w = tw[k << (9 - st)];
      float wy = INV ? -w.y : w.y;
      float2 bw = make_float2(b.x * w.x - b.y * wy, b.x * wy + b.y * w.x);
      int d0 = ((j >> st) << (st + 1)) | k;
      dst[d0]      = make_float2(a.x + bw.x, a.y + bw.y);
      dst[d0 + Ns] = make_float2(a.x - bw.x, a.y - bw.y);
    }
    float2* tmp = src; src = dst; dst = tmp;
  }
  __syncthreads();  // result in X
}

// ------------------------------------------------- k23: scores + paired row FFT
// Block = 16 q-rows of one head. Scores in MFMA regs (K streamed via L2),
// scattered into LDS X per row-pair, FFT'd, half-spectra -> transposed Ct.
__global__ __launch_bounds__(256) void k23_scores_fft(
    const short* __restrict__ Q, const short* __restrict__ Kb,
    __half2* __restrict__ Ct, int bh0)
{
  __shared__ float2 XY[2048];          // X | Y
  __shared__ float2 tw[512];
  __shared__ __half2 Fbuf[16 * 513];
  __shared__ __align__(16) short Qs[16 * 80];
  float2* X = XY;
  float2* Y = XY + 1024;
  const int tid = threadIdx.x;
  const int q0 = blockIdx.x * 16;      // 64 q-groups
  const int z = blockIdx.y;            // head within chunk
  const int lane = tid & 63, w = tid >> 6;
  const int lm = lane & 15, lq = lane >> 4;
  init_tw(tw, tid);
  const short* __restrict__ Qp = Q + ((size_t)(bh0 + z) << 16);
  const short* __restrict__ Kp = Kb + ((size_t)(bh0 + z) << 16);
  if (tid < 128) {
    int row = tid >> 3, sl = tid & 7;
    *(int4*)&Qs[row * 80 + sl * 8] = *(const int4*)&Qp[(size_t)(q0 + row) * 64 + sl * 8];
  }
  __syncthreads();

  f32x4 acc[16] = {};
  short8 af0 = *(const short8*)&Qs[lm * 80 + lq * 8];
  short8 af1 = *(const short8*)&Qs[lm * 80 + 32 + lq * 8];
#pragma unroll
  for (int t = 0; t < 16; ++t) {
    int n0 = (w * 16 + t) * 16;
    short8 b0 = *(const short8*)&Kp[(size_t)(n0 + lm) * 64 + lq * 8];
    short8 b1 = *(const short8*)&Kp[(size_t)(n0 + lm) * 64 + 32 + lq * 8];
    acc[t] = __builtin_amdgcn_mfma_f32_16x16x32_bf16(af0, b0, acc[t], 0, 0, 0);
    acc[t] = __builtin_amdgcn_mfma_f32_16x16x32_bf16(af1, b1, acc[t], 0, 0, 0);
  }

#pragma unroll 1
  for (int p = 0; p < 8; ++p) {
    __syncthreads();  // X free (prior unpack done)
    if (lq == (p >> 1)) {
      // rows 2p,2p+1 live in acc regs r0, r0+1 of quad p>>1
#pragma unroll
      for (int t = 0; t < 16; ++t) {
        float lo = (p & 1) ? acc[t][2] : acc[t][0];
        float hi = (p & 1) ? acc[t][3] : acc[t][1];
        X[(w * 16 + t) * 16 + lm] = make_float2(lo * 0.125f, hi * 0.125f);
      }
    }
    fft1024<false>(X, Y, tw, tid);
    for (int v = tid; v < 513; v += 256) {
      int wn = (1024 - v) & 1023;
      float2 A = X[v], B = X[wn];
      // F1 = (Z + conj(Z~))/2 ; F2 = (Z - conj(Z~))/(2i)
      Fbuf[(2 * p) * 513 + v]     = __float22half2_rn(make_float2((A.x + B.x) * 0.5f, (A.y - B.y) * 0.5f));
      Fbuf[(2 * p + 1) * 513 + v] = __float22half2_rn(make_float2((A.y + B.y) * 0.5f, (B.x - A.x) * 0.5f));
    }
  }
  __syncthreads();
  __half2* out = Ct + (size_t)z * 513 * 1024;
  for (int id = tid; id < 2052; id += 256) {
    int v = id >> 2, qq = (id & 3) * 4;
    int4 o;
    __half2* op = (__half2*)&o;
#pragma unroll
    for (int i = 0; i < 4; ++i) op[i] = Fbuf[(qq + i) * 513 + v];
    *(int4*)&out[(size_t)v * 1024 + q0 + qq] = o;
  }
}

// ------------------------------------------------- k4: column FFT + gain + iFFT
__global__ __launch_bounds__(256) void k4_colfft(__half2* __restrict__ Ct,
                                                  const int* __restrict__ flags)
{
  __shared__ float2 tile[4 * 1024];
  __shared__ float2 tw[512];
  const int tid = threadIdx.x;
  const int v0 = blockIdx.x * 4;
  const int z = blockIdx.y;
  const float alpha = ((const float*)flags)[1];
  init_tw(tw, tid);
  __half2* base = Ct + (size_t)z * 513 * 1024;

  for (int i = tid; i < 4096; i += 256) {
    int c = i >> 10, q = i & 1023, gv = v0 + c;
    tile[i] = (gv < 513) ? __half22float2(base[(size_t)gv * 1024 + q]) : make_float2(0.f, 0.f);
  }
  for (int s = 10; s >= 1; --s) {
    const int half = 1 << (s - 1);
    __syncthreads();
    for (int i = tid; i < 2048; i += 256) {
      int c = i >> 9, b = i & 511;
      int k = b & (half - 1), blk = b >> (s - 1);
      int i0 = (c << 10) | (blk << s) | k, i1 = i0 + half;
      float2 x0 = tile[i0], x1 = tile[i1];
      float2 w = tw[k << (10 - s)];
      float2 d = make_float2(x0.x - x1.x, x0.y - x1.y);
      tile[i0] = make_float2(x0.x + x1.x, x0.y + x1.y);
      tile[i1] = make_float2(d.x * w.x - d.y * w.y, d.x * w.y + d.y * w.x);
    }
  }
  __syncthreads();
  for (int i = tid; i < 4096; i += 256) {
    float2 f = tile[i];
    float mag2 = f.x * f.x + f.y * f.y;
    float wf = __cosf(alpha * atanf(0.5f * __logf(mag2 + 1e-20f))) * (1.0f / 1048576.0f);
    tile[i] = make_float2(f.x * wf, f.y * wf);
  }
  for (int s = 1; s <= 10; ++s) {
    const int half = 1 << (s - 1);
    __syncthreads();
    for (int i = tid; i < 2048; i += 256) {
      int c = i >> 9, b = i & 511;
      int k = b & (half - 1), blk = b >> (s - 1);
      int i0 = (c << 10) | (blk << s) | k, i1 = i0 + half;
      float2 x0 = tile[i0], x1 = tile[i1];
      float2 w = tw[k << (10 - s)];
      float2 tt = make_float2(x1.x * w.x + x1.y * w.y, x1.y * w.x - x1.x * w.y);
      tile[i0] = make_float2(x0.x + tt.x, x0.y + tt.y);
      tile[i1] = make_float2(x0.x - tt.x, x0.y - tt.y);
    }
  }
  __syncthreads();
  for (int i = tid; i < 4096; i += 256) {
    int c = i >> 10, q = i & 1023, gv = v0 + c;
    if (gv < 513) base[(size_t)gv * 1024 + q] = __float22half2_rn(tile[i]);
  }
}

// ------------------------------------------------- k56: inverse row FFT + softmax + PV
// GP overlay: P rows (bf16, pitch 2080B, from byte 0) grow while Gbuf rows
// (half2, pitch 2052B, from byte 448) are consumed: P rows {2p,2p+1} end at
// (2p+2)*2080 <= 448 + (2p+2)*2052  (equality at p=7)  => never clobbers
// a live Gbuf row.
__global__ __launch_bounds__(256) void k56_softmax_av(
    const __half2* __restrict__ Ct, const short* __restrict__ Vt,
    short* __restrict__ ctx, int bh0)
{
  __shared__ float2 XY[2048];
  __shared__ float2 tw[512];
  __shared__ __align__(16) char GP[33280];
  __shared__ float2 rbuf[4];
  float2* X = XY;
  float2* Y = XY + 1024;
  const int tid = threadIdx.x;
  const int q0 = blockIdx.x * 16, z = blockIdx.y;
  const int lane = tid & 63, w = tid >> 6;
  const int lm = lane & 15, lq = lane >> 4;
  init_tw(tw, tid);
  const __half2* __restrict__ in = Ct + (size_t)z * 513 * 1024;
#define GROW(m) ((__half2*)(GP + 448 + (m) * 2052))
  for (int id = tid; id < 2052; id += 256) {
    int v = id >> 2, qq = (id & 3) * 4;
    int4 o = *(const int4*)&in[(size_t)v * 1024 + q0 + qq];
    __half2* op = (__half2*)&o;
#pragma unroll
    for (int i = 0; i < 4; ++i) GROW(qq + i)[v] = op[i];
  }
  short* P = (short*)GP;  // row m at m*1040 shorts

#pragma unroll 1
  for (int p = 0; p < 8; ++p) {
    __syncthreads();  // Gbuf ready (p=0) / X free + P writes visible (p>0)
    const __half2* g1 = GROW(2 * p);
    const __half2* g2 = GROW(2 * p + 1);
    for (int v = tid; v < 1024; v += 256) {
      float2 a, b;
      if (v <= 512) {
        a = __half22float2(g1[v]);
        b = __half22float2(g2[v]);
      } else {
        int wn = 1024 - v;
        float2 aa = __half22float2(g1[wn]), bb = __half22float2(g2[wn]);
        a = make_float2(aa.x, -aa.y);
        b = make_float2(bb.x, -bb.y);
      }
      X[v] = make_float2(a.x - b.y, a.y + b.x);  // G1 + i*G2
    }
    fft1024<true>(X, Y, tw, tid);  // Re = row 2p, Im = row 2p+1

    float m1 = -3.4e38f, m2 = -3.4e38f;
    for (int v = tid; v < 1024; v += 256) { m1 = fmaxf(m1, X[v].x); m2 = fmaxf(m2, X[v].y); }
#pragma unroll
    for (int s = 32; s > 0; s >>= 1) {
      m1 = fmaxf(m1, __shfl_xor(m1, s, 64));
      m2 = fmaxf(m2, __shfl_xor(m2, s, 64));
    }
    if (lane == 0) rbuf[w] = make_float2(m1, m2);
    __syncthreads();
    float gm1 = fmaxf(fmaxf(rbuf[0].x, rbuf[1].x), fmaxf(rbuf[2].x, rbuf[3].x));
    float gm2 = fmaxf(fmaxf(rbuf[0].y, rbuf[1].y), fmaxf(rbuf[2].y, rbuf[3].y));
    __syncthreads();
    float s1 = 0.f, s2 = 0.f;
    for (int v = tid; v < 1024; v += 256) {
      float e1 = __expf(X[v].x - gm1), e2 = __expf(X[v].y - gm2);
      Y[v] = make_float2(e1, e2);
      s1 += e1; s2 += e2;
    }
#pragma unroll
    for (int s = 32; s > 0; s >>= 1) {
      s1 += __shfl_xor(s1, s, 64);
      s2 += __shfl_xor(s2, s, 64);
    }
    if (lane == 0) rbuf[w] = make_float2(s1, s2);
    __syncthreads();
    float inv1 = 1.0f / (rbuf[0].x + rbuf[1].x + rbuf[2].x + rbuf[3].x);
    float inv2 = 1.0f / (rbuf[0].y + rbuf[1].y + rbuf[2].y + rbuf[3].y);
    for (int v = tid; v < 1024; v += 256) {
      P[(2 * p) * 1040 + v]     = f2bf(Y[v].x * inv1);
      P[(2 * p + 1) * 1040 + v] = f2bf(Y[v].y * inv2);
    }
  }
  __syncthreads();  // P complete; X/Y free

  // PV: wave w covers k in [w*256, w*256+256); 4 d-tiles of 16
  const short* __restrict__ Vp = Vt + ((size_t)(bh0 + z) << 16);
  f32x4 acc[4] = {};
#pragma unroll
  for (int ks = 0; ks < 8; ++ks) {
    int k0 = w * 256 + ks * 32;
    short8 a0 = *(const short8*)&P[lm * 1040 + k0 + lq * 8];
#pragma unroll
    for (int b = 0; b < 4; ++b) {
      short8 bv = *(const short8*)&Vp[(size_t)(b * 16 + lm) * 1024 + k0 + lq * 8];
      acc[b] = __builtin_amdgcn_mfma_f32_16x16x32_bf16(a0, bv, acc[b], 0, 0, 0);
    }
  }
  float* red = (float*)XY;  // [w][q=16][d=64] = 4096 floats
#pragma unroll
  for (int b = 0; b < 4; ++b)
#pragma unroll
    for (int r = 0; r < 4; ++r)
      red[(w * 16 + lq * 4 + r) * 64 + b * 16 + lm] = acc[b][r];
  __syncthreads();
  {
    int q = tid >> 4, d0 = (tid & 15) * 4;
    float s0 = 0.f, s1 = 0.f, s2 = 0.f, s3 = 0.f;
#pragma unroll
    for (int ww = 0; ww < 4; ++ww) {
      const float* rr = &red[(ww * 16 + q) * 64 + d0];
      s0 += rr[0]; s1 += rr[1]; s2 += rr[2]; s3 += rr[3];
    }
    short o4[4] = {f2bf(s0), f2bf(s1), f2bf(s2), f2bf(s3)};
    *(int2*)&ctx[(((size_t)(bh0 + z)) << 16) + (size_t)(q0 + q) * 64 + d0] = *(int2*)o4;
  }
#undef GROW
}

// ------------------------------------------------- k7: out = ctx @ Wo^T + bo (XCD-swizzled)
__global__ __launch_bounds__(256) void k7_out(
    const short* __restrict__ ctx, const void* __restrict__ Wo,
    const void* __restrict__ bo, void* __restrict__ out,
    const int* __restrict__ flags)
{
  __shared__ __align__(16) char smem[128 * 136 * 2];
  short* As = (short*)smem;
  short* Bs = As + 128 * PITCH;
  short* Ct = (short*)smem;
  const int isf32 = flags[0];
  const int t = threadIdx.x;
  const int lb = blockIdx.x;
  const int m0 = ((lb & 7) * 4 + ((lb >> 3) & 3)) * 128;
  const int n0 = (lb >> 5) * 128;
  const int lane = t & 63, wvi = t >> 6;
  const int wr = wvi >> 1, wc = wvi & 1;
  const int lm = lane & 15, lq = lane >> 4;
  f32x4 acc[4][4] = {};

  for (int k0 = 0; k0 < 1024; k0 += 32) {
    __syncthreads();
#pragma unroll
    for (int i = 0; i < 2; ++i) {
      int l = t + i * 256;
      int row = l >> 2, kk = (l & 3) << 3;
      int n = m0 + row, e = k0 + kk;
      size_t aaddr = (((size_t)((n >> 10) * 16 + (e >> 6))) << 16) + (size_t)((n & 1023) << 6) + (e & 63);
      *(int4*)&As[row * PITCH + kk] = *(const int4*)&ctx[aaddr];
      *(short8*)&Bs[row * PITCH + kk] = ld8(Wo, (size_t)(n0 + row) * 1024 + e, isf32);
    }
    __syncthreads();
    short8 af[4], bf[4];
#pragma unroll
    for (int a = 0; a < 4; ++a) af[a] = *(const short8*)&As[(wr * 64 + a * 16 + lm) * PITCH + lq * 8];
#pragma unroll
    for (int b = 0; b < 4; ++b) bf[b] = *(const short8*)&Bs[(wc * 64 + b * 16 + lm) * PITCH + lq * 8];
#pragma unroll
    for (int a = 0; a < 4; ++a)
#pragma unroll
      for (int b = 0; b < 4; ++b)
        acc[a][b] = __builtin_amdgcn_mfma_f32_16x16x32_bf16(af[a], bf[b], acc[a][b], 0, 0, 0);
  }

  if (isf32) {
#pragma unroll
    for (int a = 0; a < 4; ++a)
#pragma unroll
      for (int b = 0; b < 4; ++b) {
        int col = n0 + wc * 64 + b * 16 + lm;
        float bo_ = ldf(bo, col, 1);
#pragma unroll
        for (int r = 0; r < 4; ++r) {
          int row = m0 + wr * 64 + a * 16 + lq * 4 + r;
          ((float*)out)[(size_t)row * 1024 + col] = acc[a][b][r] + bo_;
        }
      }
    return;
  }
  __syncthreads();
#pragma unroll
  for (int a = 0; a < 4; ++a)
#pragma unroll
    for (int b = 0; b < 4; ++b) {
      int col = wc * 64 + b * 16 + lm;
      float bo_ = ldf(bo, n0 + col, 0);
#pragma unroll
      for (int r = 0; r < 4; ++r) {
        int row = wr * 64 + a * 16 + lq * 4 + r;
        Ct[row * 136 + col] = f2bf(acc[a][b][r] + bo_);
      }
    }
  __syncthreads();
#pragma unroll
  for (int j = 0; j < 8; ++j) {
    int id = t + j * 256;
    int row = id >> 4, c16 = (id & 15) * 8;
    short8 v = *(const short8*)&Ct[row * 136 + c16];
    *(short8*)&((short*)out)[(size_t)(m0 + row) * 1024 + n0 + c16] = v;
  }
}

// ------------------------------------------------- launch
extern "C" void kernel_launch(void* const* d_in, const int* in_sizes, int n_in,
                              void* d_out, int out_size, void* d_ws, size_t ws_size,
                              hipStream_t stream)
{
  const void* x  = d_in[0];
  const void* Wq = d_in[1];
  const void* bq = d_in[2];
  const void* Wk = d_in[3];
  const void* bk = d_in[4];
  const void* Wv = d_in[5];
  const void* bv = d_in[6];
  const void* Wo = d_in[7];
  const void* bo = d_in[8];
  const void* alphap = d_in[9];
  char* ws = (char*)d_ws;

  short*   Q    = (short*)(ws);
  short*   Kb   = (short*)(ws + (size_t)( 8u << 20));
  short*   Vt   = (short*)(ws + (size_t)(16u << 20));
  short*   ctx  = (short*)(ws + (size_t)(24u << 20));
  __half2* Ct   = (__half2*)(ws + (size_t)(32u << 20));  // 16*513*1024*4 B
  int*     flags = (int*)(ws + (size_t)(32u << 20) + (size_t)16 * 513 * 1024 * 4);

  k0_detect<<<1, 256, 0, stream>>>((const unsigned*)x, alphap, flags);
  k1_qkv<<<dim3(256, 3), 256, 0, stream>>>(x, Wq, bq, Wk, bk, Wv, bv, Q, Kb, Vt, flags);
  for (int c = 0; c < 4; ++c) {
    int bh0 = c * 16;
    k23_scores_fft<<<dim3(64, 16), 256, 0, stream>>>(Q, Kb, Ct, bh0);
    k4_colfft<<<dim3(129, 16), 256, 0, stream>>>(Ct, flags);
    k56_softmax_av<<<dim3(64, 16), 256, 0, stream>>>(Ct, Vt, ctx, bh0);
  }
  k7_out<<<256, 256, 0, stream>>>(ctx, Wo, bo, d_out, flags);
}

// Round 5
// 1014.749 us; speedup vs baseline: 1.6939x; 1.2720x over previous
//
#include <hip/hip_runtime.h>
#include <hip/hip_fp16.h>

// SpectralAttention: B=4, S=1024, E=1024, H=16, HD=64.
// Identity: real(ifft2(F*exp(i*phi))) == ifft2(F * cos(phi)) for real scores
// => real spectral gain, Hermitian half-spectrum (v=0..512).
//
// Round-5: all 1024-pt FFTs are radix-4, IN-PLACE (DIF natural->digit-rev,
// elementwise ops in digit-rev domain via dr4(), DIT digit-rev->natural),
// with LDS pad phys(i)=i+(i>>4) to kill power-of-2-stride bank conflicts.
//
// Workspace (~64.1 MiB): Q 8M | Kb 8M | Vt 8M | ctx 8M | Ct 32.06M | flags

typedef __attribute__((ext_vector_type(8))) short short8;
typedef __attribute__((ext_vector_type(4))) float f32x4;

#define PITCH 40
#define PADI(i) ((i) + ((i) >> 4))   // 1024 logical -> 1088 physical float2
#define XROW 1088

__device__ __forceinline__ float bf2f(short v) {
  return __uint_as_float(((unsigned)(unsigned short)v) << 16);
}
__device__ __forceinline__ short f2bf(float f) {
  unsigned u = __float_as_uint(f);
  u += 0x7FFFu + ((u >> 16) & 1u);  // RNE
  return (short)(u >> 16);
}

__device__ __forceinline__ short8 ld8(const void* p, size_t idx, int isf32) {
  short8 r;
  if (isf32) {
    const float* f = (const float*)p + idx;
    float4 a = *(const float4*)f;
    float4 b = *(const float4*)(f + 4);
    r[0] = f2bf(a.x); r[1] = f2bf(a.y); r[2] = f2bf(a.z); r[3] = f2bf(a.w);
    r[4] = f2bf(b.x); r[5] = f2bf(b.y); r[6] = f2bf(b.z); r[7] = f2bf(b.w);
  } else {
    r = *(const short8*)((const short*)p + idx);
  }
  return r;
}
__device__ __forceinline__ float ldf(const void* p, int idx, int isf32) {
  return isf32 ? ((const float*)p)[idx] : bf2f(((const short*)p)[idx]);
}

__device__ __forceinline__ float2 cmul(float2 a, float2 b) {
  return make_float2(a.x * b.x - a.y * b.y, a.x * b.y + a.y * b.x);
}
__device__ __forceinline__ float2 cmulc(float2 a, float2 b) {  // a * conj(b)
  return make_float2(a.x * b.x + a.y * b.y, a.y * b.x - a.x * b.y);
}
// base-4 digit reversal of 10-bit index (involution)
__device__ __forceinline__ int dr4(int p) {
  return ((p & 3) << 8) | (((p >> 2) & 3) << 6) | (((p >> 4) & 3) << 4) |
         (((p >> 6) & 3) << 2) | ((p >> 8) & 3);
}

// ------------------------------------------------- k0: dtype detect + alpha
__global__ void k0_detect(const unsigned* __restrict__ q,
                          const void* __restrict__ alphap, int* __restrict__ flags) {
  __shared__ float smax[256];
  __shared__ int szero[256];
  int t = threadIdx.x;
  float mx = 0.f; int zc = 0;
  for (int i = t; i < 16384; i += 256) {
    unsigned w = q[i];
    unsigned lo = w & 0xFFFFu;
    float v = fabsf(__uint_as_float(lo << 16));
    if (!(v <= 1e30f)) v = 1e30f;
    mx = fmaxf(mx, v);
    zc += (lo == 0u);
  }
  smax[t] = mx; szero[t] = zc;
  __syncthreads();
  for (int s = 128; s > 0; s >>= 1) {
    if (t < s) { smax[t] = fmaxf(smax[t], smax[t + s]); szero[t] += szero[t + s]; }
    __syncthreads();
  }
  if (t == 0) {
    int isf32 = (smax[0] > 100.f) || (szero[0] > 12288);
    flags[0] = isf32;
    float alpha = isf32 ? *(const float*)alphap : bf2f(*(const short*)alphap);
    ((float*)flags)[1] = alpha;
  }
}

// ------------------------------------------------- k1: QKV projection (XCD-swizzled)
__global__ __launch_bounds__(256) void k1_qkv(
    const void* __restrict__ x,
    const void* __restrict__ Wq, const void* __restrict__ bq,
    const void* __restrict__ Wk, const void* __restrict__ bk,
    const void* __restrict__ Wv, const void* __restrict__ bv,
    short* __restrict__ Qo, short* __restrict__ Ko, short* __restrict__ Vt,
    const int* __restrict__ flags)
{
  __shared__ __align__(16) char smem[128 * 136 * 2];
  short* As = (short*)smem;
  short* Bs = As + 128 * PITCH;
  short* Ct = (short*)smem;
  const int isf32 = flags[0];
  const int t = threadIdx.x;
  const int lb = blockIdx.x;
  const int m0 = ((lb & 7) * 4 + ((lb >> 3) & 3)) * 128;
  const int n0 = (lb >> 5) * 128;
  const int which = blockIdx.y;
  const void* __restrict__ W = (which == 0) ? Wq : (which == 1) ? Wk : Wv;
  const void* __restrict__ bias = (which == 0) ? bq : (which == 1) ? bk : bv;
  const int lane = t & 63, wvi = t >> 6;
  const int wr = wvi >> 1, wc = wvi & 1;
  const int lm = lane & 15, lq = lane >> 4;
  f32x4 acc[4][4] = {};

  for (int k0 = 0; k0 < 1024; k0 += 32) {
    __syncthreads();
#pragma unroll
    for (int i = 0; i < 2; ++i) {
      int l = t + i * 256;
      int row = l >> 2, kk = (l & 3) << 3;
      *(short8*)&As[row * PITCH + kk] = ld8(x, (size_t)(m0 + row) * 1024 + k0 + kk, isf32);
      *(short8*)&Bs[row * PITCH + kk] = ld8(W, (size_t)(n0 + row) * 1024 + k0 + kk, isf32);
    }
    __syncthreads();
    short8 af[4], bf[4];
#pragma unroll
    for (int a = 0; a < 4; ++a) af[a] = *(const short8*)&As[(wr * 64 + a * 16 + lm) * PITCH + lq * 8];
#pragma unroll
    for (int b = 0; b < 4; ++b) bf[b] = *(const short8*)&Bs[(wc * 64 + b * 16 + lm) * PITCH + lq * 8];
#pragma unroll
    for (int a = 0; a < 4; ++a)
#pragma unroll
      for (int b = 0; b < 4; ++b)
        acc[a][b] = __builtin_amdgcn_mfma_f32_16x16x32_bf16(af[a], bf[b], acc[a][b], 0, 0, 0);
  }

  __syncthreads();
#pragma unroll
  for (int a = 0; a < 4; ++a)
#pragma unroll
    for (int b = 0; b < 4; ++b) {
      int col = wc * 64 + b * 16 + lm;
      float bv_ = ldf(bias, n0 + col, isf32);
#pragma unroll
      for (int r = 0; r < 4; ++r) {
        int row = wr * 64 + a * 16 + lq * 4 + r;
        Ct[row * 136 + col] = f2bf(acc[a][b][r] + bv_);
      }
    }
  __syncthreads();

  if (which != 2) {
    short* __restrict__ O = (which == 1) ? Ko : Qo;
#pragma unroll
    for (int j = 0; j < 8; ++j) {
      int id = t + j * 256;
      int row = id >> 4, c16 = (id & 15) * 8;
      short8 v = *(const short8*)&Ct[row * 136 + c16];
      int col = n0 + c16;
      int h = col >> 6, d = col & 63;
      int n = m0 + row, bb = n >> 10, s = n & 1023;
      *(short8*)&O[(((size_t)(bb * 16 + h)) << 16) + ((size_t)s << 6) + d] = v;
    }
  } else {
#pragma unroll
    for (int j = 0; j < 8; ++j) {
      int id = t + j * 256;
      int d128 = id & 127, sg = (id >> 7) * 8;
      short vals[8];
#pragma unroll
      for (int i = 0; i < 8; ++i) vals[i] = Ct[(sg + i) * 136 + d128];
      int col = n0 + d128;
      int h = col >> 6, d = col & 63;
      int bb = m0 >> 10, sbase = (m0 & 1023) + sg;
      *(short8*)&Vt[(((size_t)(bb * 16 + h)) << 16) + ((size_t)d << 10) + sbase] = *(short8*)vals;
    }
  }
}

// ------------------------------------------------- FFT helpers
__device__ __forceinline__ void init_tw(float2* tw, int tid) {
  for (int j = tid; j < 512; j += 256) {
    float a = (float)j * (6.283185307179586f / 1024.0f);
    float s, c;
    __sincosf(a, &s, &c);
    tw[j] = make_float2(c, -s);  // W_1024^j
  }
}

// In-place radix-4, padded X (XROW float2), 256 threads, 1 butterfly/thread/stage.
// fwd: natural -> digit-reversed.  inv: digit-reversed -> natural (unnormalized).
template <bool INV>
__device__ __forceinline__ void fftr4(float2* X, const float2* tw, int tid) {
#pragma unroll
  for (int si = 0; si < 5; ++si) {
    const int st = INV ? 4 - si : si;
    const int L = 1024 >> (2 * st), q = L >> 2, sh = 8 - 2 * st;
    __syncthreads();
    int k = tid & (q - 1), g = tid >> sh;
    int idx = g * L + k;
    int e = k << (2 * st);
    float2 w1 = tw[e], w2 = tw[2 * e];
    int i0 = PADI(idx), i1 = PADI(idx + q), i2 = PADI(idx + 2 * q), i3 = PADI(idx + 3 * q);
    float2 x0 = X[i0], x1 = X[i1], x2 = X[i2], x3 = X[i3];
    if (!INV) {
      float2 w3 = cmul(w1, w2);
      float2 t0 = make_float2(x0.x + x2.x, x0.y + x2.y);
      float2 t1 = make_float2(x0.x - x2.x, x0.y - x2.y);
      float2 t2 = make_float2(x1.x + x3.x, x1.y + x3.y);
      float2 t3 = make_float2(x1.x - x3.x, x1.y - x3.y);
      X[i0] = make_float2(t0.x + t2.x, t0.y + t2.y);
      X[i1] = cmul(make_float2(t1.x + t3.y, t1.y - t3.x), w1);  // t1 - i t3
      X[i2] = cmul(make_float2(t0.x - t2.x, t0.y - t2.y), w2);
      X[i3] = cmul(make_float2(t1.x - t3.y, t1.y + t3.x), w3);  // t1 + i t3
    } else {
      float2 w3 = cmul(w1, w2);
      float2 y1 = cmulc(x1, w1), y2 = cmulc(x2, w2), y3 = cmulc(x3, w3);
      float2 t0 = make_float2(x0.x + y2.x, x0.y + y2.y);
      float2 t1 = make_float2(x0.x - y2.x, x0.y - y2.y);
      float2 t2 = make_float2(y1.x + y3.x, y1.y + y3.y);
      float2 t3 = make_float2(y1.x - y3.x, y1.y - y3.y);
      X[i0] = make_float2(t0.x + t2.x, t0.y + t2.y);
      X[i1] = make_float2(t1.x - t3.y, t1.y + t3.x);  // t1 + i t3
      X[i2] = make_float2(t0.x - t2.x, t0.y - t2.y);
      X[i3] = make_float2(t1.x + t3.y, t1.y - t3.x);  // t1 - i t3
    }
  }
  __syncthreads();
}

// ------------------------------------------------- k23: scores + paired row FFT
__global__ __launch_bounds__(256) void k23_scores_fft(
    const short* __restrict__ Q, const short* __restrict__ Kb,
    __half2* __restrict__ Ct, int bh0)
{
  __shared__ float2 X[XROW];
  __shared__ float2 tw[512];
  __shared__ __half2 Fbuf[16 * 513];
  __shared__ __align__(16) short Qs[16 * 80];
  const int tid = threadIdx.x;
  const int q0 = blockIdx.x * 16;
  const int z = blockIdx.y;
  const int lane = tid & 63, w = tid >> 6;
  const int lm = lane & 15, lq = lane >> 4;
  init_tw(tw, tid);
  const short* __restrict__ Qp = Q + ((size_t)(bh0 + z) << 16);
  const short* __restrict__ Kp = Kb + ((size_t)(bh0 + z) << 16);
  if (tid < 128) {
    int row = tid >> 3, sl = tid & 7;
    *(int4*)&Qs[row * 80 + sl * 8] = *(const int4*)&Qp[(size_t)(q0 + row) * 64 + sl * 8];
  }
  __syncthreads();

  f32x4 acc[16] = {};
  short8 af0 = *(const short8*)&Qs[lm * 80 + lq * 8];
  short8 af1 = *(const short8*)&Qs[lm * 80 + 32 + lq * 8];
#pragma unroll
  for (int t = 0; t < 16; ++t) {
    int n0 = (w * 16 + t) * 16;
    short8 b0 = *(const short8*)&Kp[(size_t)(n0 + lm) * 64 + lq * 8];
    short8 b1 = *(const short8*)&Kp[(size_t)(n0 + lm) * 64 + 32 + lq * 8];
    acc[t] = __builtin_amdgcn_mfma_f32_16x16x32_bf16(af0, b0, acc[t], 0, 0, 0);
    acc[t] = __builtin_amdgcn_mfma_f32_16x16x32_bf16(af1, b1, acc[t], 0, 0, 0);
  }

#pragma unroll 1
  for (int p = 0; p < 8; ++p) {
    __syncthreads();  // X free (prior unpack done)
    if (lq == (p >> 1)) {
#pragma unroll
      for (int t = 0; t < 16; ++t) {
        float lo = (p & 1) ? acc[t][2] : acc[t][0];
        float hi = (p & 1) ? acc[t][3] : acc[t][1];
        X[PADI((w * 16 + t) * 16 + lm)] = make_float2(lo * 0.125f, hi * 0.125f);
      }
    }
    fftr4<false>(X, tw, tid);  // digit-reversed result
    for (int v = tid; v < 513; v += 256) {
      int wn = (1024 - v) & 1023;
      float2 A = X[PADI(dr4(v))], B = X[PADI(dr4(wn))];
      // F1 = (Z + conj(Z~))/2 ; F2 = (Z - conj(Z~))/(2i)
      Fbuf[(2 * p) * 513 + v]     = __float22half2_rn(make_float2((A.x + B.x) * 0.5f, (A.y - B.y) * 0.5f));
      Fbuf[(2 * p + 1) * 513 + v] = __float22half2_rn(make_float2((A.y + B.y) * 0.5f, (B.x - A.x) * 0.5f));
    }
  }
  __syncthreads();
  __half2* out = Ct + (size_t)z * 513 * 1024;
  for (int id = tid; id < 2052; id += 256) {
    int v = id >> 2, qq = (id & 3) * 4;
    int4 o;
    __half2* op = (__half2*)&o;
#pragma unroll
    for (int i = 0; i < 4; ++i) op[i] = Fbuf[(qq + i) * 513 + v];
    *(int4*)&out[(size_t)v * 1024 + q0 + qq] = o;
  }
}

// ------------------------------------------------- k4: column FFT + gain + iFFT
// 4 v-rows per block, radix-4 in-place, padded rows (XROW float2 each).
__global__ __launch_bounds__(256) void k4_colfft(__half2* __restrict__ Ct,
                                                  const int* __restrict__ flags)
{
  __shared__ float2 tile[4 * XROW];
  __shared__ float2 tw[512];
  const int tid = threadIdx.x;
  const int v0 = blockIdx.x * 4;
  const int z = blockIdx.y;
  const float alpha = ((const float*)flags)[1];
  init_tw(tw, tid);
  __half2* base = Ct + (size_t)z * 513 * 1024;

  for (int i = tid; i < 4096; i += 256) {
    int c = i >> 10, q = i & 1023, gv = v0 + c;
    tile[c * XROW + PADI(q)] =
        (gv < 513) ? __half22float2(base[(size_t)gv * 1024 + q]) : make_float2(0.f, 0.f);
  }
  // forward radix-4 DIF (natural -> digit-reversed)
#pragma unroll
  for (int st = 0; st < 5; ++st) {
    const int L = 1024 >> (2 * st), q = L >> 2, sh = 8 - 2 * st;
    __syncthreads();
    int k = tid & (q - 1), g = tid >> sh;
    int idx = g * L + k;
    int e = k << (2 * st);
    float2 w1 = tw[e], w2 = tw[2 * e];
    float2 w3 = cmul(w1, w2);
#pragma unroll
    for (int c = 0; c < 4; ++c) {
      int bb = c * XROW;
      int i0 = bb + PADI(idx), i1 = bb + PADI(idx + q), i2 = bb + PADI(idx + 2 * q), i3 = bb + PADI(idx + 3 * q);
      float2 x0 = tile[i0], x1 = tile[i1], x2 = tile[i2], x3 = tile[i3];
      float2 t0 = make_float2(x0.x + x2.x, x0.y + x2.y);
      float2 t1 = make_float2(x0.x - x2.x, x0.y - x2.y);
      float2 t2 = make_float2(x1.x + x3.x, x1.y + x3.y);
      float2 t3 = make_float2(x1.x - x3.x, x1.y - x3.y);
      tile[i0] = make_float2(t0.x + t2.x, t0.y + t2.y);
      tile[i1] = cmul(make_float2(t1.x + t3.y, t1.y - t3.x), w1);
      tile[i2] = cmul(make_float2(t0.x - t2.x, t0.y - t2.y), w2);
      tile[i3] = cmul(make_float2(t1.x - t3.y, t1.y + t3.x), w3);
    }
  }
  __syncthreads();
  // real spectral gain (elementwise, order-invariant); 1/N^2 folded in
  for (int i = tid; i < 4096; i += 256) {
    int c = i >> 10, q = i & 1023;
    float2 f = tile[c * XROW + PADI(q)];
    float mag2 = f.x * f.x + f.y * f.y;
    float wf = __cosf(alpha * atanf(0.5f * __logf(mag2 + 1e-20f))) * (1.0f / 1048576.0f);
    tile[c * XROW + PADI(q)] = make_float2(f.x * wf, f.y * wf);
  }
  // inverse radix-4 DIT (digit-reversed -> natural)
#pragma unroll
  for (int st = 4; st >= 0; --st) {
    const int L = 1024 >> (2 * st), q = L >> 2, sh = 8 - 2 * st;
    __syncthreads();
    int k = tid & (q - 1), g = tid >> sh;
    int idx = g * L + k;
    int e = k << (2 * st);
    float2 w1 = tw[e], w2 = tw[2 * e];
    float2 w3 = cmul(w1, w2);
#pragma unroll
    for (int c = 0; c < 4; ++c) {
      int bb = c * XROW;
      int i0 = bb + PADI(idx), i1 = bb + PADI(idx + q), i2 = bb + PADI(idx + 2 * q), i3 = bb + PADI(idx + 3 * q);
      float2 x0 = tile[i0], x1 = tile[i1], x2 = tile[i2], x3 = tile[i3];
      float2 y1 = cmulc(x1, w1), y2 = cmulc(x2, w2), y3 = cmulc(x3, w3);
      float2 t0 = make_float2(x0.x + y2.x, x0.y + y2.y);
      float2 t1 = make_float2(x0.x - y2.x, x0.y - y2.y);
      float2 t2 = make_float2(y1.x + y3.x, y1.y + y3.y);
      float2 t3 = make_float2(y1.x - y3.x, y1.y - y3.y);
      tile[i0] = make_float2(t0.x + t2.x, t0.y + t2.y);
      tile[i1] = make_float2(t1.x - t3.y, t1.y + t3.x);
      tile[i2] = make_float2(t0.x - t2.x, t0.y - t2.y);
      tile[i3] = make_float2(t1.x + t3.y, t1.y - t3.x);
    }
  }
  __syncthreads();
  for (int i = tid; i < 4096; i += 256) {
    int c = i >> 10, q = i & 1023, gv = v0 + c;
    if (gv < 513) base[(size_t)gv * 1024 + q] = __float22half2_rn(tile[c * XROW + PADI(q)]);
  }
}

// ------------------------------------------------- k56: inverse row FFT + softmax + PV
// GP overlay: P rows (bf16, pitch 2080B, from 0) grow while Gbuf rows (half2,
// pitch 2052B, from 448) are consumed; (2p+2)*2080 <= 448+(2p+2)*2052 for p<8.
__global__ __launch_bounds__(256) void k56_softmax_av(
    const __half2* __restrict__ Ct, const short* __restrict__ Vt,
    short* __restrict__ ctx, int bh0)
{
  __shared__ float2 X[XROW];
  __shared__ float2 tw[512];
  __shared__ __align__(16) char GP[33280];
  __shared__ float2 rbuf[4];
  const int tid = threadIdx.x;
  const int q0 = blockIdx.x * 16, z = blockIdx.y;
  const int lane = tid & 63, w = tid >> 6;
  const int lm = lane & 15, lq = lane >> 4;
  init_tw(tw, tid);
  const __half2* __restrict__ in = Ct + (size_t)z * 513 * 1024;
#define GROW(m) ((__half2*)(GP + 448 + (m) * 2052))
  for (int id = tid; id < 2052; id += 256) {
    int v = id >> 2, qq = (id & 3) * 4;
    int4 o = *(const int4*)&in[(size_t)v * 1024 + q0 + qq];
    __half2* op = (__half2*)&o;
#pragma unroll
    for (int i = 0; i < 4; ++i) GROW(qq + i)[v] = op[i];
  }
  short* P = (short*)GP;  // row m at m*1040 shorts

#pragma unroll 1
  for (int p = 0; p < 8; ++p) {
    __syncthreads();  // Gbuf ready (p=0) / X free + P visible (p>0)
    const __half2* g1 = GROW(2 * p);
    const __half2* g2 = GROW(2 * p + 1);
    for (int v = tid; v < 1024; v += 256) {
      float2 a, b;
      if (v <= 512) {
        a = __half22float2(g1[v]);
        b = __half22float2(g2[v]);
      } else {
        int wn = 1024 - v;
        float2 aa = __half22float2(g1[wn]), bb = __half22float2(g2[wn]);
        a = make_float2(aa.x, -aa.y);
        b = make_float2(bb.x, -bb.y);
      }
      X[PADI(dr4(v))] = make_float2(a.x - b.y, a.y + b.x);  // G1 + i*G2, digit-rev
    }
    fftr4<true>(X, tw, tid);  // natural order; Re = row 2p, Im = row 2p+1

    float m1 = -3.4e38f, m2 = -3.4e38f;
    for (int v = tid; v < 1024; v += 256) {
      float2 xv = X[PADI(v)];
      m1 = fmaxf(m1, xv.x); m2 = fmaxf(m2, xv.y);
    }
#pragma unroll
    for (int s = 32; s > 0; s >>= 1) {
      m1 = fmaxf(m1, __shfl_xor(m1, s, 64));
      m2 = fmaxf(m2, __shfl_xor(m2, s, 64));
    }
    if (lane == 0) rbuf[w] = make_float2(m1, m2);
    __syncthreads();
    float gm1 = fmaxf(fmaxf(rbuf[0].x, rbuf[1].x), fmaxf(rbuf[2].x, rbuf[3].x));
    float gm2 = fmaxf(fmaxf(rbuf[0].y, rbuf[1].y), fmaxf(rbuf[2].y, rbuf[3].y));
    __syncthreads();
    float s1 = 0.f, s2 = 0.f;
    for (int v = tid; v < 1024; v += 256) {
      float2 xv = X[PADI(v)];
      float e1 = __expf(xv.x - gm1), e2 = __expf(xv.y - gm2);
      X[PADI(v)] = make_float2(e1, e2);
      s1 += e1; s2 += e2;
    }
#pragma unroll
    for (int s = 32; s > 0; s >>= 1) {
      s1 += __shfl_xor(s1, s, 64);
      s2 += __shfl_xor(s2, s, 64);
    }
    if (lane == 0) rbuf[w] = make_float2(s1, s2);
    __syncthreads();
    float inv1 = 1.0f / (rbuf[0].x + rbuf[1].x + rbuf[2].x + rbuf[3].x);
    float inv2 = 1.0f / (rbuf[0].y + rbuf[1].y + rbuf[2].y + rbuf[3].y);
    for (int v = tid; v < 1024; v += 256) {
      float2 xv = X[PADI(v)];
      P[(2 * p) * 1040 + v]     = f2bf(xv.x * inv1);
      P[(2 * p + 1) * 1040 + v] = f2bf(xv.y * inv2);
    }
  }
  __syncthreads();  // P complete

  // PV: wave w covers k in [w*256, w*256+256)
  const short* __restrict__ Vp = Vt + ((size_t)(bh0 + z) << 16);
  f32x4 acc[4] = {};
#pragma unroll
  for (int ks = 0; ks < 8; ++ks) {
    int k0 = w * 256 + ks * 32;
    short8 a0 = *(const short8*)&P[lm * 1040 + k0 + lq * 8];
#pragma unroll
    for (int b = 0; b < 4; ++b) {
      short8 bv = *(const short8*)&Vp[(size_t)(b * 16 + lm) * 1024 + k0 + lq * 8];
      acc[b] = __builtin_amdgcn_mfma_f32_16x16x32_bf16(a0, bv, acc[b], 0, 0, 0);
    }
  }
  __syncthreads();  // all P reads done; reuse GP for reduction
  float* red = (float*)GP;  // [w][q=16][d=64]
#pragma unroll
  for (int b = 0; b < 4; ++b)
#pragma unroll
    for (int r = 0; r < 4; ++r)
      red[(w * 16 + lq * 4 + r) * 64 + b * 16 + lm] = acc[b][r];
  __syncthreads();
  {
    int q = tid >> 4, d0 = (tid & 15) * 4;
    float s0 = 0.f, s1 = 0.f, s2 = 0.f, s3 = 0.f;
#pragma unroll
    for (int ww = 0; ww < 4; ++ww) {
      const float* rr = &red[(ww * 16 + q) * 64 + d0];
      s0 += rr[0]; s1 += rr[1]; s2 += rr[2]; s3 += rr[3];
    }
    short o4[4] = {f2bf(s0), f2bf(s1), f2bf(s2), f2bf(s3)};
    *(int2*)&ctx[(((size_t)(bh0 + z)) << 16) + (size_t)(q0 + q) * 64 + d0] = *(int2*)o4;
  }
#undef GROW
}

// ------------------------------------------------- k7: out = ctx @ Wo^T + bo (XCD-swizzled)
__global__ __launch_bounds__(256) void k7_out(
    const short* __restrict__ ctx, const void* __restrict__ Wo,
    const void* __restrict__ bo, void* __restrict__ out,
    const int* __restrict__ flags)
{
  __shared__ __align__(16) char smem[128 * 136 * 2];
  short* As = (short*)smem;
  short* Bs = As + 128 * PITCH;
  short* Ct = (short*)smem;
  const int isf32 = flags[0];
  const int t = threadIdx.x;
  const int lb = blockIdx.x;
  const int m0 = ((lb & 7) * 4 + ((lb >> 3) & 3)) * 128;
  const int n0 = (lb >> 5) * 128;
  const int lane = t & 63, wvi = t >> 6;
  const int wr = wvi >> 1, wc = wvi & 1;
  const int lm = lane & 15, lq = lane >> 4;
  f32x4 acc[4][4] = {};

  for (int k0 = 0; k0 < 1024; k0 += 32) {
    __syncthreads();
#pragma unroll
    for (int i = 0; i < 2; ++i) {
      int l = t + i * 256;
      int row = l >> 2, kk = (l & 3) << 3;
      int n = m0 + row, e = k0 + kk;
      size_t aaddr = (((size_t)((n >> 10) * 16 + (e >> 6))) << 16) + (size_t)((n & 1023) << 6) + (e & 63);
      *(int4*)&As[row * PITCH + kk] = *(const int4*)&ctx[aaddr];
      *(short8*)&Bs[row * PITCH + kk] = ld8(Wo, (size_t)(n0 + row) * 1024 + e, isf32);
    }
    __syncthreads();
    short8 af[4], bf[4];
#pragma unroll
    for (int a = 0; a < 4; ++a) af[a] = *(const short8*)&As[(wr * 64 + a * 16 + lm) * PITCH + lq * 8];
#pragma unroll
    for (int b = 0; b < 4; ++b) bf[b] = *(const short8*)&Bs[(wc * 64 + b * 16 + lm) * PITCH + lq * 8];
#pragma unroll
    for (int a = 0; a < 4; ++a)
#pragma unroll
      for (int b = 0; b < 4; ++b)
        acc[a][b] = __builtin_amdgcn_mfma_f32_16x16x32_bf16(af[a], bf[b], acc[a][b], 0, 0, 0);
  }

  if (isf32) {
#pragma unroll
    for (int a = 0; a < 4; ++a)
#pragma unroll
      for (int b = 0; b < 4; ++b) {
        int col = n0 + wc * 64 + b * 16 + lm;
        float bo_ = ldf(bo, col, 1);
#pragma unroll
        for (int r = 0; r < 4; ++r) {
          int row = m0 + wr * 64 + a * 16 + lq * 4 + r;
          ((float*)out)[(size_t)row * 1024 + col] = acc[a][b][r] + bo_;
        }
      }
    return;
  }
  __syncthreads();
#pragma unroll
  for (int a = 0; a < 4; ++a)
#pragma unroll
    for (int b = 0; b < 4; ++b) {
      int col = wc * 64 + b * 16 + lm;
      float bo_ = ldf(bo, n0 + col, 0);
#pragma unroll
      for (int r = 0; r < 4; ++r) {
        int row = wr * 64 + a * 16 + lq * 4 + r;
        Ct[row * 136 + col] = f2bf(acc[a][b][r] + bo_);
      }
    }
  __syncthreads();
#pragma unroll
  for (int j = 0; j < 8; ++j) {
    int id = t + j * 256;
    int row = id >> 4, c16 = (id & 15) * 8;
    short8 v = *(const short8*)&Ct[row * 136 + c16];
    *(short8*)&((short*)out)[(size_t)(m0 + row) * 1024 + n0 + c16] = v;
  }
}

// ------------------------------------------------- launch
extern "C" void kernel_launch(void* const* d_in, const int* in_sizes, int n_in,
                              void* d_out, int out_size, void* d_ws, size_t ws_size,
                              hipStream_t stream)
{
  const void* x  = d_in[0];
  const void* Wq = d_in[1];
  const void* bq = d_in[2];
  const void* Wk = d_in[3];
  const void* bk = d_in[4];
  const void* Wv = d_in[5];
  const void* bv = d_in[6];
  const void* Wo = d_in[7];
  const void* bo = d_in[8];
  const void* alphap = d_in[9];
  char* ws = (char*)d_ws;

  short*   Q    = (short*)(ws);
  short*   Kb   = (short*)(ws + (size_t)( 8u << 20));
  short*   Vt   = (short*)(ws + (size_t)(16u << 20));
  short*   ctx  = (short*)(ws + (size_t)(24u << 20));
  __half2* Ct   = (__half2*)(ws + (size_t)(32u << 20));
  int*     flags = (int*)(ws + (size_t)(32u << 20) + (size_t)16 * 513 * 1024 * 4);

  k0_detect<<<1, 256, 0, stream>>>((const unsigned*)x, alphap, flags);
  k1_qkv<<<dim3(256, 3), 256, 0, stream>>>(x, Wq, bq, Wk, bk, Wv, bv, Q, Kb, Vt, flags);
  for (int c = 0; c < 4; ++c) {
    int bh0 = c * 16;
    k23_scores_fft<<<dim3(64, 16), 256, 0, stream>>>(Q, Kb, Ct, bh0);
    k4_colfft<<<dim3(129, 16), 256, 0, stream>>>(Ct, flags);
    k56_softmax_av<<<dim3(64, 16), 256, 0, stream>>>(Ct, Vt, ctx, bh0);
  }
  k7_out<<<256, 256, 0, stream>>>(ctx, Wo, bo, d_out, flags);
}